// Round 1
// baseline (2621.774 us; speedup 1.0000x reference)
//
#include <hip/hip_runtime.h>
#include <stdint.h>

// ---- problem constants ----
#define NB   32        // batch
#define NCH  128       // num atoms
#define IMG  64
#define IMG2 4096      // 64*64
#define OH   57        // 64-8+1
#define OHW  3249      // 57*57
#define CHW  415872    // 128*3249 (per-sample code size)
#define KTOP 256       // sparsity K
#define NATT 17        // alphas 2^0 .. 2^-16 (while count<=15 semantics)
#define CAP  16384     // candidate capacity per sample
#define NBUCK 2048     // |g| histogram buckets (top 11 bits of float)
#define TGT  900       // collect at least this many top-|g| entries (need >=512)

// ---------------- init: support count = 0 ----------------
__global__ void k_init(int* support_cnt) {
    if (threadIdx.x < NB) support_cnt[threadIdx.x] = 0;
}

// ---------------- zero hist + cand counters ----------------
__global__ void k_zero(uint32_t* hist, int* cand_cnt) {
    int i = blockIdx.x * 256 + threadIdx.x;
    if (i < NB * NBUCK) hist[i] = 0;
    if (i < NB) cand_cnt[i] = 0;
}

// ---------------- R = Y - D*X (sparse scatter), l2 = sum R^2 ----------------
__global__ __launch_bounds__(256) void k_resid(
    const float* __restrict__ Y, const float* __restrict__ W,
    const int* __restrict__ support_cnt, const uint32_t* __restrict__ support_idx,
    const float* __restrict__ support_val, float* __restrict__ Rg, double* __restrict__ l2part)
{
    int b = blockIdx.x, tid = threadIdx.x;
    __shared__ float Rs[IMG2];
    const float4* Y4 = (const float4*)(Y + b * IMG2);
    float4* R4 = (float4*)Rs;
    for (int i = tid; i < IMG2 / 4; i += 256) R4[i] = Y4[i];
    __syncthreads();
    int n = support_cnt[b];
    for (int task = tid; task < n * 64; task += 256) {
        int i = task >> 6, tap = task & 63, p = tap >> 3, q = tap & 7;
        uint32_t idx = support_idx[b * KTOP + i];
        float val = support_val[b * KTOP + i];
        int c = idx / OHW, rem = idx % OHW, s = rem / OH, t = rem % OH;
        float w = W[c * 64 + p * 8 + q];              // W[c,0,p,q]
        atomicAdd(&Rs[(s + p) * IMG + (t + q)], -val * w);
    }
    __syncthreads();
    double acc = 0.0;
    for (int i = tid; i < IMG2; i += 256) {
        float v = Rs[i];
        Rg[b * IMG2 + i] = v;
        acc += (double)v * (double)v;
    }
    __shared__ double red[256];
    red[tid] = acc; __syncthreads();
    for (int s2 = 128; s2 > 0; s2 >>= 1) { if (tid < s2) red[tid] += red[tid + s2]; __syncthreads(); }
    if (tid == 0) l2part[b] = red[0];
}

// ---------------- g = D^T * R (dense, fp32 vector) + |g| histogram ----------------
// grid (NB, 64): 2 channels per block. Thread tile: 8 rows x 4 cols of g.
// g[b,c,s,t] = sum_{p,q} R[s+p,t+q] * W[c,0,q,p]   (Wt = swapaxes(W,2,3))
__global__ __launch_bounds__(256) void k_conv(
    const float* __restrict__ Rg, const float* __restrict__ W,
    float* __restrict__ g_out, uint32_t* __restrict__ hist)
{
    int b = blockIdx.x, cg = blockIdx.y, tid = threadIdx.x;
    __shared__ float Rs[72 * 72];
    __shared__ uint32_t hl[NBUCK];
    for (int i = tid; i < 72 * 72; i += 256) Rs[i] = 0.f;
    for (int i = tid; i < NBUCK; i += 256) hl[i] = 0u;
    __syncthreads();
    const float4* R4 = (const float4*)(Rg + b * IMG2);
    for (int i = tid; i < 1024; i += 256) {
        int row = i >> 4, col4 = (i & 15) * 4;
        *(float4*)&Rs[row * 72 + col4] = R4[i];
    }
    __syncthreads();
    int csub = tid >> 7;               // wave-uniform (waves 0,1 -> 0; 2,3 -> 1)
    int tile = tid & 127;              // valid < 120
    bool active = tile < 120;
    int tr = active ? tile / 15 : 0;
    int tc = active ? tile % 15 : 0;
    int s0 = tr * 8, t0 = tc * 4;
    int c = cg * 2 + csub;
    int c_s = __builtin_amdgcn_readfirstlane(c);   // force scalar weight loads
    const float* Wc = W + c_s * 64;

    float acc[8][4];
#pragma unroll
    for (int r = 0; r < 8; ++r)
#pragma unroll
        for (int cc = 0; cc < 4; ++cc) acc[r][cc] = 0.f;

#pragma unroll
    for (int rho = 0; rho < 15; ++rho) {
        float rb[12];
        const float* rp = &Rs[(s0 + rho) * 72 + t0];
        *(float4*)&rb[0] = *(const float4*)rp;
        *(float4*)&rb[4] = *(const float4*)(rp + 4);
        *(float4*)&rb[8] = *(const float4*)(rp + 8);
#pragma unroll
        for (int r = 0; r < 8; ++r) {
            const int p = rho - r;
            if (p >= 0 && p < 8) {
#pragma unroll
                for (int q = 0; q < 8; ++q) {
                    float wv = Wc[q * 8 + p];      // Wt[c,0,p,q] = W[c,0,q,p]
#pragma unroll
                    for (int cc = 0; cc < 4; ++cc)
                        acc[r][cc] = fmaf(rb[cc + q], wv, acc[r][cc]);
                }
            }
        }
    }
    if (active) {
        float* go = g_out + (size_t)(b * NCH + c) * OHW;
#pragma unroll
        for (int r = 0; r < 8; ++r) {
            int s = s0 + r;
            if (s < OH) {
#pragma unroll
                for (int cc = 0; cc < 4; ++cc) {
                    int t = t0 + cc;
                    if (t < OH) {
                        float v = acc[r][cc];
                        go[s * OH + t] = v;
                        uint32_t bits = __float_as_uint(v) & 0x7fffffffu;
                        atomicAdd(&hl[bits >> 21], 1u);
                    }
                }
            }
        }
    }
    __syncthreads();
    for (int i = tid; i < NBUCK; i += 256) {
        uint32_t v = hl[i];
        if (v) atomicAdd(&hist[b * NBUCK + i], v);
    }
}

// ---------------- per-sample bucket threshold: top >= TGT entries ----------------
__global__ void k_thresh(const uint32_t* __restrict__ hist, uint32_t* __restrict__ thr) {
    int b = threadIdx.x;
    if (b >= NB) return;
    uint32_t cum = 0; int bk = 0;
    for (int i = NBUCK - 1; i >= 0; --i) {
        cum += hist[b * NBUCK + i];
        if (cum >= TGT) { bk = i; break; }
    }
    thr[b] = (uint32_t)bk << 21;
}

// ---------------- collect candidates: |g| above bucket threshold ----------------
// grid ((CHW/4+255)/256, NB); 4 elements per thread
__global__ __launch_bounds__(256) void k_collect(
    const float* __restrict__ g, const uint32_t* __restrict__ thr,
    int* __restrict__ cand_cnt, uint32_t* __restrict__ cand_idx, float* __restrict__ cand_g)
{
    int b = blockIdx.y;
    int i4 = blockIdx.x * 256 + threadIdx.x;
    if (i4 >= CHW / 4) return;
    uint32_t tb = thr[b];
    float4 v4 = ((const float4*)(g + (size_t)b * CHW))[i4];
    float vv[4] = { v4.x, v4.y, v4.z, v4.w };
#pragma unroll
    for (int k = 0; k < 4; ++k) {
        uint32_t bits = __float_as_uint(vv[k]) & 0x7fffffffu;
        if (bits >= tb) {
            int pos = atomicAdd(&cand_cnt[b], 1);
            if (pos < CAP) {
                cand_idx[b * CAP + pos] = (uint32_t)(i4 * 4 + k);
                cand_g[b * CAP + pos] = vv[k];
            }
        }
    }
}

// ---------------- add support entries not collected; resolve x for all ----------------
__global__ __launch_bounds__(256) void k_suppg(
    const float* __restrict__ g, const uint32_t* __restrict__ thr,
    const int* __restrict__ support_cnt, const uint32_t* __restrict__ support_idx,
    const float* __restrict__ support_val,
    int* __restrict__ cand_cnt, uint32_t* __restrict__ cand_idx,
    float* __restrict__ cand_g, float* __restrict__ cand_x)
{
    int b = blockIdx.x, tid = threadIdx.x;
    __shared__ uint32_t sidx[KTOP];
    __shared__ float sval[KTOP];
    int n = support_cnt[b];
    if (tid < n) { sidx[tid] = support_idx[b * KTOP + tid]; sval[tid] = support_val[b * KTOP + tid]; }
    __syncthreads();
    if (tid < n) {
        uint32_t idx = sidx[tid];
        float gv = g[(size_t)b * CHW + idx];
        uint32_t bits = __float_as_uint(gv) & 0x7fffffffu;
        if (bits < thr[b]) {
            int pos = atomicAdd(&cand_cnt[b], 1);
            if (pos < CAP) { cand_idx[b * CAP + pos] = idx; cand_g[b * CAP + pos] = gv; }
        }
    }
    __threadfence();
    __syncthreads();
    __shared__ int nc_s;
    if (tid == 0) nc_s = min(atomicAdd(&cand_cnt[b], 0), CAP);
    __syncthreads();
    int nc = nc_s;
    for (int j = tid; j < nc; j += 256) {
        uint32_t q = cand_idx[b * CAP + j];
        float x = 0.f;
        int lo = 0, hi = n - 1;
        while (lo <= hi) {
            int mid = (lo + hi) >> 1;
            uint32_t m = sidx[mid];
            if (m == q) { x = sval[mid]; break; }
            if (m < q) lo = mid + 1; else hi = mid - 1;
        }
        cand_x[b * CAP + j] = x;
    }
}

// ---------------- one line-search attempt: exact top-256 + err ----------------
// grid (NATT, NB). v_i = x_i + alpha*g_i (fmaf form, identical across passes).
__global__ __launch_bounds__(256) void k_attempt(
    const float* __restrict__ Y, const float* __restrict__ W,
    const int* __restrict__ cand_cnt, const uint32_t* __restrict__ cand_idx,
    const float* __restrict__ cand_g, const float* __restrict__ cand_x,
    uint32_t* __restrict__ sel_idx, float* __restrict__ sel_val, double* __restrict__ err)
{
    int a = blockIdx.x, b = blockIdx.y, tid = threadIdx.x;
    float alpha = ldexpf(1.f, -a);
    int nc = min(cand_cnt[b], CAP);
    const uint32_t* ci = cand_idx + b * CAP;
    const float* cgp = cand_g + b * CAP;
    const float* cxp = cand_x + b * CAP;

    __shared__ uint32_t hl[256];
    __shared__ uint32_t sh_prefix;
    __shared__ int sh_rem;
    __shared__ int nsel, ntie;
    __shared__ uint32_t s_cidx[KTOP];
    __shared__ float s_v[KTOP];
    __shared__ uint32_t tie_i[512];
    __shared__ float recon[IMG2];
    __shared__ double red[256];

    if (tid == 0) { sh_prefix = 0u; sh_rem = KTOP; nsel = 0; ntie = 0; }
    s_cidx[tid] = 0u; s_v[tid] = 0.f;
    __syncthreads();

    // 4-pass radix select (descending) for the exact 256th-largest |v| bit pattern
    for (int pass = 0; pass < 4; ++pass) {
        hl[tid] = 0u;
        __syncthreads();
        uint32_t pre = sh_prefix;
        int shift = 24 - 8 * pass;
        for (int i = tid; i < nc; i += 256) {
            float v = fmaf(alpha, cgp[i], cxp[i]);
            uint32_t key = __float_as_uint(fabsf(v));
            bool ok = (pass == 0) || ((key >> (shift + 8)) == pre);
            if (ok) atomicAdd(&hl[(key >> shift) & 255], 1u);
        }
        __syncthreads();
        if (tid == 0) {
            uint32_t cum = 0; int rem = sh_rem; uint32_t pre2 = sh_prefix;
            for (int bin = 255; bin >= 0; --bin) {
                uint32_t cnt = hl[bin];
                if (cum + cnt >= (uint32_t)rem) {
                    sh_rem = rem - (int)cum;
                    sh_prefix = (pre2 << 8) | (uint32_t)bin;
                    break;
                }
                cum += cnt;
            }
        }
        __syncthreads();
    }
    uint32_t T = sh_prefix; int rem = sh_rem;

    // gather strictly-greater + ties
    for (int i = tid; i < nc; i += 256) {
        float v = fmaf(alpha, cgp[i], cxp[i]);
        uint32_t key = __float_as_uint(fabsf(v));
        if (key > T) {
            int p = atomicAdd(&nsel, 1);
            if (p < KTOP) { s_cidx[p] = ci[i]; s_v[p] = v; }
        } else if (key == T) {
            int p = atomicAdd(&ntie, 1);
            if (p < 512) tie_i[p] = (uint32_t)i;
        }
    }
    __syncthreads();
    if (tid == 0) {
        int nt = min(ntie, 512);
        int base = min(nsel, KTOP);
        for (int k = 0; k < rem && base + k < KTOP; ++k) {   // smallest flat idx first (lax.top_k tie order)
            uint32_t best = 0xffffffffu; int bj = -1;
            for (int j = 0; j < nt; ++j) {
                uint32_t t2 = tie_i[j];
                if (t2 == 0xffffffffu) continue;
                uint32_t fidx = ci[t2];
                if (fidx < best) { best = fidx; bj = j; }
            }
            if (bj < 0) break;
            uint32_t i2 = tie_i[bj]; tie_i[bj] = 0xffffffffu;
            float v = fmaf(alpha, cgp[i2], cxp[i2]);
            s_cidx[base + k] = ci[i2]; s_v[base + k] = v;
        }
    }
    __syncthreads();
    sel_idx[((size_t)a * NB + b) * KTOP + tid] = s_cidx[tid];
    sel_val[((size_t)a * NB + b) * KTOP + tid] = s_v[tid];

    // reconstruction + err
    for (int i = tid; i < IMG2; i += 256) recon[i] = 0.f;
    __syncthreads();
    for (int task = tid; task < KTOP * 64; task += 256) {
        int i = task >> 6, tap = task & 63, p = tap >> 3, q = tap & 7;
        uint32_t idx = s_cidx[i];
        float val = s_v[i];
        int c = idx / OHW, remn = idx % OHW, s = remn / OH, t = remn % OH;
        atomicAdd(&recon[(s + p) * IMG + (t + q)], val * W[c * 64 + p * 8 + q]);
    }
    __syncthreads();
    double accd = 0.0;
    for (int e = tid; e < IMG2; e += 256) {
        float d = Y[b * IMG2 + e] - recon[e];
        accd += (double)d * (double)d;
    }
    red[tid] = accd; __syncthreads();
    for (int s2 = 128; s2 > 0; s2 >>= 1) { if (tid < s2) red[tid] += red[tid + s2]; __syncthreads(); }
    if (tid == 0) err[a * NB + b] = red[0];
}

// ---------------- replay while-loop: first alpha with err < l2_start ----------------
__global__ void k_select(const double* __restrict__ l2part, const double* __restrict__ err,
                         int* __restrict__ sel_a) {
    if (threadIdx.x != 0 || blockIdx.x != 0) return;
    double l2 = 0.0;
    for (int b = 0; b < NB; ++b) l2 += l2part[b];
    int sel = NATT - 1;
    for (int a = 0; a < NATT; ++a) {
        double e = 0.0;
        for (int b = 0; b < NB; ++b) e += err[a * NB + b];
        if (e < l2) { sel = a; break; }
    }
    *sel_a = sel;
}

// ---------------- adopt selected attempt as new X (sorted support) ----------------
__global__ __launch_bounds__(256) void k_update(
    const int* __restrict__ sel_a, const uint32_t* __restrict__ sel_idx, const float* __restrict__ sel_val,
    int* __restrict__ support_cnt, uint32_t* __restrict__ support_idx, float* __restrict__ support_val)
{
    int b = blockIdx.x, tid = threadIdx.x;
    int a = *sel_a;
    __shared__ uint32_t ki[KTOP];
    __shared__ float kv[KTOP];
    ki[tid] = sel_idx[((size_t)a * NB + b) * KTOP + tid];
    kv[tid] = sel_val[((size_t)a * NB + b) * KTOP + tid];
    // bitonic sort ascending by index
    for (int k = 2; k <= KTOP; k <<= 1) {
        for (int j = k >> 1; j > 0; j >>= 1) {
            __syncthreads();
            int ixj = tid ^ j;
            if (ixj > tid) {
                uint32_t a0 = ki[tid], a1 = ki[ixj];
                float v0 = kv[tid], v1 = kv[ixj];
                bool up = ((tid & k) == 0);
                bool sw = up ? (a0 > a1) : (a0 < a1);
                if (sw) { ki[tid] = a1; ki[ixj] = a0; kv[tid] = v1; kv[ixj] = v0; }
            }
        }
    }
    __syncthreads();
    support_idx[b * KTOP + tid] = ki[tid];
    support_val[b * KTOP + tid] = kv[tid];
    if (tid == 0) support_cnt[b] = KTOP;
}

// ---------------- final output: zero + scatter ----------------
__global__ void k_outzero(float4* __restrict__ out) {
    int i = blockIdx.x * 256 + threadIdx.x;
    if (i < (NB * CHW) / 4) out[i] = make_float4(0.f, 0.f, 0.f, 0.f);
}

__global__ void k_scatter(const uint32_t* __restrict__ support_idx, const float* __restrict__ support_val,
                          float* __restrict__ out) {
    int b = blockIdx.x, tid = threadIdx.x;
    if (tid < KTOP) out[(size_t)b * CHW + support_idx[b * KTOP + tid]] = support_val[b * KTOP + tid];
}

// ---------------- host ----------------
static size_t align256(size_t x) { return (x + 255) & ~(size_t)255; }

extern "C" void kernel_launch(void* const* d_in, const int* in_sizes, int n_in,
                              void* d_out, int out_size, void* d_ws, size_t ws_size,
                              hipStream_t stream)
{
    const float* Y = (const float*)d_in[0];   // (32,1,64,64)
    const float* W = (const float*)d_in[1];   // (128,1,8,8), normalized
    float* out = (float*)d_out;               // (32,128,57,57) — doubles as dense g

    char* p = (char*)d_ws;
    size_t off = 0;
    auto carve = [&](size_t bytes) { void* r = p + off; off = align256(off + bytes); return r; };
    float*    Rg          = (float*)   carve(NB * IMG2 * sizeof(float));
    uint32_t* hist        = (uint32_t*)carve(NB * NBUCK * sizeof(uint32_t));
    uint32_t* thr         = (uint32_t*)carve(NB * sizeof(uint32_t));
    int*      cand_cnt    = (int*)     carve(NB * sizeof(int));
    double*   l2part      = (double*)  carve(NB * sizeof(double));
    double*   err         = (double*)  carve(NATT * NB * sizeof(double));
    int*      sel_a       = (int*)     carve(sizeof(int));
    int*      support_cnt = (int*)     carve(NB * sizeof(int));
    uint32_t* support_idx = (uint32_t*)carve(NB * KTOP * sizeof(uint32_t));
    float*    support_val = (float*)   carve(NB * KTOP * sizeof(float));
    uint32_t* sel_idx     = (uint32_t*)carve((size_t)NATT * NB * KTOP * sizeof(uint32_t));
    float*    sel_val     = (float*)   carve((size_t)NATT * NB * KTOP * sizeof(float));
    uint32_t* cand_idx    = (uint32_t*)carve((size_t)NB * CAP * sizeof(uint32_t));
    float*    cand_g      = (float*)   carve((size_t)NB * CAP * sizeof(float));
    float*    cand_x      = (float*)   carve((size_t)NB * CAP * sizeof(float));
    (void)ws_size; (void)in_sizes; (void)n_in; (void)out_size;  // ~8.3 MB total

    k_init<<<1, 64, 0, stream>>>(support_cnt);
    for (int t = 0; t < 3; ++t) {
        k_zero<<<(NB * NBUCK + 255) / 256, 256, 0, stream>>>(hist, cand_cnt);
        k_resid<<<NB, 256, 0, stream>>>(Y, W, support_cnt, support_idx, support_val, Rg, l2part);
        k_conv<<<dim3(NB, NCH / 2), 256, 0, stream>>>(Rg, W, out, hist);
        k_thresh<<<1, 64, 0, stream>>>(hist, thr);
        k_collect<<<dim3((CHW / 4 + 255) / 256, NB), 256, 0, stream>>>(out, thr, cand_cnt, cand_idx, cand_g);
        k_suppg<<<NB, 256, 0, stream>>>(out, thr, support_cnt, support_idx, support_val,
                                        cand_cnt, cand_idx, cand_g, cand_x);
        k_attempt<<<dim3(NATT, NB), 256, 0, stream>>>(Y, W, cand_cnt, cand_idx, cand_g, cand_x,
                                                      sel_idx, sel_val, err);
        k_select<<<1, 64, 0, stream>>>(l2part, err, sel_a);
        k_update<<<NB, 256, 0, stream>>>(sel_a, sel_idx, sel_val, support_cnt, support_idx, support_val);
    }
    k_outzero<<<((NB * CHW) / 4 + 255) / 256, 256, 0, stream>>>((float4*)out);
    k_scatter<<<NB, 256, 0, stream>>>(support_idx, support_val, out);
}

// Round 2
// 1495.670 us; speedup vs baseline: 1.7529x; 1.7529x over previous
//
#include <hip/hip_runtime.h>
#include <stdint.h>

// ---- problem constants ----
#define NB   32        // batch
#define NCH  128       // num atoms
#define IMG  64
#define IMG2 4096      // 64*64
#define OH   57        // 64-8+1
#define OHW  3249      // 57*57
#define CHW  415872    // 128*3249 (per-sample code size)
#define KTOP 256       // sparsity K
#define NATT 17        // alphas 2^0 .. 2^-16 (while count<=15 semantics)
#define NS   32        // candidate counter slices per sample (atomic spread)
#define SCAP 512       // capacity per slice
#define CAP2 8192      // compacted candidate capacity per sample
#define NBUCK 2048     // |g| histogram buckets (top 11 bits of float)
#define TGT  900       // collect at least this many top-|g| entries (need >=512)

// ---------------- init: support count = 0 ----------------
__global__ void k_init(int* support_cnt) {
    if (threadIdx.x < NB) support_cnt[threadIdx.x] = 0;
}

// ---------------- zero hist + sliced cand counters ----------------
__global__ void k_zero(uint32_t* hist, int* cand_cnt) {
    int i = blockIdx.x * 256 + threadIdx.x;
    if (i < NB * NBUCK) hist[i] = 0;
    if (i < NB * NS) cand_cnt[i] = 0;
}

// ---------------- R = Y - D*X (sparse scatter), l2 = sum R^2 ----------------
__global__ __launch_bounds__(256) void k_resid(
    const float* __restrict__ Y, const float* __restrict__ W,
    const int* __restrict__ support_cnt, const uint32_t* __restrict__ support_idx,
    const float* __restrict__ support_val, float* __restrict__ Rg, double* __restrict__ l2part)
{
    int b = blockIdx.x, tid = threadIdx.x;
    __shared__ float Rs[IMG2];
    const float4* Y4 = (const float4*)(Y + b * IMG2);
    float4* R4 = (float4*)Rs;
    for (int i = tid; i < IMG2 / 4; i += 256) R4[i] = Y4[i];
    __syncthreads();
    int n = support_cnt[b];
    for (int task = tid; task < n * 64; task += 256) {
        int i = task >> 6, tap = task & 63, p = tap >> 3, q = tap & 7;
        uint32_t idx = support_idx[b * KTOP + i];
        float val = support_val[b * KTOP + i];
        int c = idx / OHW, rem = idx % OHW, s = rem / OH, t = rem % OH;
        float w = W[c * 64 + p * 8 + q];              // W[c,0,p,q]
        atomicAdd(&Rs[(s + p) * IMG + (t + q)], -val * w);
    }
    __syncthreads();
    double acc = 0.0;
    for (int i = tid; i < IMG2; i += 256) {
        float v = Rs[i];
        Rg[b * IMG2 + i] = v;
        acc += (double)v * (double)v;
    }
    __shared__ double red[256];
    red[tid] = acc; __syncthreads();
    for (int s2 = 128; s2 > 0; s2 >>= 1) { if (tid < s2) red[tid] += red[tid + s2]; __syncthreads(); }
    if (tid == 0) l2part[b] = red[0];
}

// ---------------- g = D^T * R (dense, fp32 vector) + |g| histogram ----------------
// grid (NB, 64): 2 channels per block. Thread tile: 8 rows x 4 cols of g.
// g[b,c,s,t] = sum_{p,q} R[s+p,t+q] * W[c,0,q,p]   (Wt = swapaxes(W,2,3))
__global__ __launch_bounds__(256) void k_conv(
    const float* __restrict__ Rg, const float* __restrict__ W,
    float* __restrict__ g_out, uint32_t* __restrict__ hist)
{
    int b = blockIdx.x, cg = blockIdx.y, tid = threadIdx.x;
    __shared__ float Rs[72 * 72];
    __shared__ uint32_t hl[NBUCK];
    for (int i = tid; i < 72 * 72; i += 256) Rs[i] = 0.f;
    for (int i = tid; i < NBUCK; i += 256) hl[i] = 0u;
    __syncthreads();
    const float4* R4 = (const float4*)(Rg + b * IMG2);
    for (int i = tid; i < 1024; i += 256) {
        int row = i >> 4, col4 = (i & 15) * 4;
        *(float4*)&Rs[row * 72 + col4] = R4[i];
    }
    __syncthreads();
    int csub = tid >> 7;               // wave-uniform (waves 0,1 -> 0; 2,3 -> 1)
    int tile = tid & 127;              // valid < 120
    bool active = tile < 120;
    int tr = active ? tile / 15 : 0;
    int tc = active ? tile % 15 : 0;
    int s0 = tr * 8, t0 = tc * 4;
    int c = cg * 2 + csub;
    int c_s = __builtin_amdgcn_readfirstlane(c);   // force scalar weight loads
    const float* Wc = W + c_s * 64;

    float acc[8][4];
#pragma unroll
    for (int r = 0; r < 8; ++r)
#pragma unroll
        for (int cc = 0; cc < 4; ++cc) acc[r][cc] = 0.f;

#pragma unroll
    for (int rho = 0; rho < 15; ++rho) {
        float rb[12];
        const float* rp = &Rs[(s0 + rho) * 72 + t0];
        *(float4*)&rb[0] = *(const float4*)rp;
        *(float4*)&rb[4] = *(const float4*)(rp + 4);
        *(float4*)&rb[8] = *(const float4*)(rp + 8);
#pragma unroll
        for (int r = 0; r < 8; ++r) {
            const int p = rho - r;
            if (p >= 0 && p < 8) {
#pragma unroll
                for (int q = 0; q < 8; ++q) {
                    float wv = Wc[q * 8 + p];      // Wt[c,0,p,q] = W[c,0,q,p]
#pragma unroll
                    for (int cc = 0; cc < 4; ++cc)
                        acc[r][cc] = fmaf(rb[cc + q], wv, acc[r][cc]);
                }
            }
        }
    }
    if (active) {
        float* go = g_out + (size_t)(b * NCH + c) * OHW;
#pragma unroll
        for (int r = 0; r < 8; ++r) {
            int s = s0 + r;
            if (s < OH) {
#pragma unroll
                for (int cc = 0; cc < 4; ++cc) {
                    int t = t0 + cc;
                    if (t < OH) {
                        float v = acc[r][cc];
                        go[s * OH + t] = v;
                        uint32_t bits = __float_as_uint(v) & 0x7fffffffu;
                        atomicAdd(&hl[bits >> 21], 1u);
                    }
                }
            }
        }
    }
    __syncthreads();
    for (int i = tid; i < NBUCK; i += 256) {
        uint32_t v = hl[i];
        if (v) atomicAdd(&hist[b * NBUCK + i], v);
    }
}

// ---------------- per-sample bucket threshold: top >= TGT entries ----------------
__global__ void k_thresh(const uint32_t* __restrict__ hist, uint32_t* __restrict__ thr) {
    int b = threadIdx.x;
    if (b >= NB) return;
    uint32_t cum = 0; int bk = 0;
    for (int i = NBUCK - 1; i >= 0; --i) {
        cum += hist[b * NBUCK + i];
        if (cum >= TGT) { bk = i; break; }
    }
    thr[b] = (uint32_t)bk << 21;
}

// ---------------- collect candidates: |g| above bucket threshold ----------------
// grid ((CHW/4+255)/256, NB); 4 elements per thread.
// Sliced counters (NS per sample) to avoid same-cacheline atomic serialization.
__global__ __launch_bounds__(256) void k_collect(
    const float* __restrict__ g, const uint32_t* __restrict__ thr,
    int* __restrict__ cand_cnt, uint32_t* __restrict__ cand_idx, float* __restrict__ cand_g)
{
    int b = blockIdx.y;
    int i4 = blockIdx.x * 256 + threadIdx.x;
    if (i4 >= CHW / 4) return;
    int slice = blockIdx.x & (NS - 1);
    uint32_t tb = thr[b];
    float4 v4 = ((const float4*)(g + (size_t)b * CHW))[i4];
    float vv[4] = { v4.x, v4.y, v4.z, v4.w };
#pragma unroll
    for (int k = 0; k < 4; ++k) {
        uint32_t bits = __float_as_uint(vv[k]) & 0x7fffffffu;
        if (bits >= tb) {
            int pos = atomicAdd(&cand_cnt[b * NS + slice], 1);
            if (pos < SCAP) {
                cand_idx[(b * NS + slice) * SCAP + pos] = (uint32_t)(i4 * 4 + k);
                cand_g[(b * NS + slice) * SCAP + pos] = vv[k];
            }
        }
    }
}

// ---------------- compact slices; add missing support entries; resolve x ----------------
__global__ __launch_bounds__(256) void k_suppg(
    const float* __restrict__ g, const uint32_t* __restrict__ thr,
    const int* __restrict__ support_cnt, const uint32_t* __restrict__ support_idx,
    const float* __restrict__ support_val,
    const int* __restrict__ cand_cnt, const uint32_t* __restrict__ cand_idx,
    const float* __restrict__ cand_g,
    uint32_t* __restrict__ c2_idx, float* __restrict__ c2_g, float* __restrict__ c2_x,
    int* __restrict__ nc_out)
{
    int b = blockIdx.x, tid = threadIdx.x;
    __shared__ uint32_t sidx[KTOP];
    __shared__ float sval[KTOP];
    __shared__ int cnts[NS];
    __shared__ int soff[NS + 1];
    __shared__ int nc_sh, extra;
    int n = support_cnt[b];
    if (tid < NS) cnts[tid] = min(cand_cnt[b * NS + tid], SCAP);
    if (tid < n) { sidx[tid] = support_idx[b * KTOP + tid]; sval[tid] = support_val[b * KTOP + tid]; }
    __syncthreads();
    if (tid == 0) {
        int acc = 0;
        for (int s = 0; s < NS; ++s) { soff[s] = acc; acc += cnts[s]; }
        soff[NS] = acc;
        nc_sh = min(acc, CAP2);
        extra = 0;
    }
    __syncthreads();
    // compact segmented -> contiguous
    for (int t = tid; t < NS * SCAP; t += 256) {
        int s = t >> 9, j = t & (SCAP - 1);
        if (j < cnts[s]) {
            int d = soff[s] + j;
            if (d < CAP2) {
                c2_idx[b * CAP2 + d] = cand_idx[(b * NS + s) * SCAP + j];
                c2_g[b * CAP2 + d] = cand_g[(b * NS + s) * SCAP + j];
            }
        }
    }
    __syncthreads();
    // append support entries below threshold (not collected)
    if (tid < n) {
        uint32_t idx = sidx[tid];
        float gv = g[(size_t)b * CHW + idx];
        uint32_t bits = __float_as_uint(gv) & 0x7fffffffu;
        if (bits < thr[b]) {
            int p = atomicAdd(&extra, 1);
            int d = nc_sh + p;
            if (d < CAP2) { c2_idx[b * CAP2 + d] = idx; c2_g[b * CAP2 + d] = gv; }
        }
    }
    __syncthreads();
    int nc = min(nc_sh + extra, CAP2);
    if (tid == 0) nc_out[b] = nc;
    // resolve x for all candidates (binary search over sorted support)
    for (int j = tid; j < nc; j += 256) {
        uint32_t q = c2_idx[b * CAP2 + j];
        float x = 0.f;
        int lo = 0, hi = n - 1;
        while (lo <= hi) {
            int mid = (lo + hi) >> 1;
            uint32_t m = sidx[mid];
            if (m == q) { x = sval[mid]; break; }
            if (m < q) lo = mid + 1; else hi = mid - 1;
        }
        c2_x[b * CAP2 + j] = x;
    }
}

// ---------------- one line-search attempt: exact top-256 + err ----------------
// grid (NATT, NB). v_i = x_i + alpha*g_i (fmaf form, identical across passes).
__global__ __launch_bounds__(256) void k_attempt(
    const float* __restrict__ Y, const float* __restrict__ W,
    const int* __restrict__ nc_in, const uint32_t* __restrict__ cand_idx,
    const float* __restrict__ cand_g, const float* __restrict__ cand_x,
    uint32_t* __restrict__ sel_idx, float* __restrict__ sel_val, double* __restrict__ err)
{
    int a = blockIdx.x, b = blockIdx.y, tid = threadIdx.x;
    float alpha = ldexpf(1.f, -a);
    int nc = min(nc_in[b], CAP2);
    const uint32_t* ci = cand_idx + b * CAP2;
    const float* cgp = cand_g + b * CAP2;
    const float* cxp = cand_x + b * CAP2;

    __shared__ uint32_t hl[256];
    __shared__ uint32_t sh_prefix;
    __shared__ int sh_rem;
    __shared__ int nsel, ntie;
    __shared__ uint32_t s_cidx[KTOP];
    __shared__ float s_v[KTOP];
    __shared__ uint32_t tie_i[512];
    __shared__ float recon[IMG2];
    __shared__ double red[256];

    if (tid == 0) { sh_prefix = 0u; sh_rem = KTOP; nsel = 0; ntie = 0; }
    s_cidx[tid] = 0u; s_v[tid] = 0.f;
    __syncthreads();

    // 4-pass radix select (descending) for the exact 256th-largest |v| bit pattern
    for (int pass = 0; pass < 4; ++pass) {
        hl[tid] = 0u;
        __syncthreads();
        uint32_t pre = sh_prefix;
        int shift = 24 - 8 * pass;
        for (int i = tid; i < nc; i += 256) {
            float v = fmaf(alpha, cgp[i], cxp[i]);
            uint32_t key = __float_as_uint(fabsf(v));
            bool ok = (pass == 0) || ((key >> (shift + 8)) == pre);
            if (ok) atomicAdd(&hl[(key >> shift) & 255], 1u);
        }
        __syncthreads();
        if (tid == 0) {
            uint32_t cum = 0; int rem = sh_rem; uint32_t pre2 = sh_prefix;
            for (int bin = 255; bin >= 0; --bin) {
                uint32_t cnt = hl[bin];
                if (cum + cnt >= (uint32_t)rem) {
                    sh_rem = rem - (int)cum;
                    sh_prefix = (pre2 << 8) | (uint32_t)bin;
                    break;
                }
                cum += cnt;
            }
        }
        __syncthreads();
    }
    uint32_t T = sh_prefix; int rem = sh_rem;

    // gather strictly-greater + ties
    for (int i = tid; i < nc; i += 256) {
        float v = fmaf(alpha, cgp[i], cxp[i]);
        uint32_t key = __float_as_uint(fabsf(v));
        if (key > T) {
            int p = atomicAdd(&nsel, 1);
            if (p < KTOP) { s_cidx[p] = ci[i]; s_v[p] = v; }
        } else if (key == T) {
            int p = atomicAdd(&ntie, 1);
            if (p < 512) tie_i[p] = (uint32_t)i;
        }
    }
    __syncthreads();
    if (tid == 0) {
        int nt = min(ntie, 512);
        int base = min(nsel, KTOP);
        for (int k = 0; k < rem && base + k < KTOP; ++k) {   // smallest flat idx first (lax.top_k tie order)
            uint32_t best = 0xffffffffu; int bj = -1;
            for (int j = 0; j < nt; ++j) {
                uint32_t t2 = tie_i[j];
                if (t2 == 0xffffffffu) continue;
                uint32_t fidx = ci[t2];
                if (fidx < best) { best = fidx; bj = j; }
            }
            if (bj < 0) break;
            uint32_t i2 = tie_i[bj]; tie_i[bj] = 0xffffffffu;
            float v = fmaf(alpha, cgp[i2], cxp[i2]);
            s_cidx[base + k] = ci[i2]; s_v[base + k] = v;
        }
    }
    __syncthreads();
    sel_idx[((size_t)a * NB + b) * KTOP + tid] = s_cidx[tid];
    sel_val[((size_t)a * NB + b) * KTOP + tid] = s_v[tid];

    // reconstruction + err
    for (int i = tid; i < IMG2; i += 256) recon[i] = 0.f;
    __syncthreads();
    for (int task = tid; task < KTOP * 64; task += 256) {
        int i = task >> 6, tap = task & 63, p = tap >> 3, q = tap & 7;
        uint32_t idx = s_cidx[i];
        float val = s_v[i];
        int c = idx / OHW, remn = idx % OHW, s = remn / OH, t = remn % OH;
        atomicAdd(&recon[(s + p) * IMG + (t + q)], val * W[c * 64 + p * 8 + q]);
    }
    __syncthreads();
    double accd = 0.0;
    for (int e = tid; e < IMG2; e += 256) {
        float d = Y[b * IMG2 + e] - recon[e];
        accd += (double)d * (double)d;
    }
    red[tid] = accd; __syncthreads();
    for (int s2 = 128; s2 > 0; s2 >>= 1) { if (tid < s2) red[tid] += red[tid + s2]; __syncthreads(); }
    if (tid == 0) err[a * NB + b] = red[0];
}

// ---------------- replay while-loop: first alpha with err < l2_start ----------------
__global__ void k_select(const double* __restrict__ l2part, const double* __restrict__ err,
                         int* __restrict__ sel_a) {
    if (threadIdx.x != 0 || blockIdx.x != 0) return;
    double l2 = 0.0;
    for (int b = 0; b < NB; ++b) l2 += l2part[b];
    int sel = NATT - 1;
    for (int a = 0; a < NATT; ++a) {
        double e = 0.0;
        for (int b = 0; b < NB; ++b) e += err[a * NB + b];
        if (e < l2) { sel = a; break; }
    }
    *sel_a = sel;
}

// ---------------- adopt selected attempt as new X (sorted support) ----------------
__global__ __launch_bounds__(256) void k_update(
    const int* __restrict__ sel_a, const uint32_t* __restrict__ sel_idx, const float* __restrict__ sel_val,
    int* __restrict__ support_cnt, uint32_t* __restrict__ support_idx, float* __restrict__ support_val)
{
    int b = blockIdx.x, tid = threadIdx.x;
    int a = *sel_a;
    __shared__ uint32_t ki[KTOP];
    __shared__ float kv[KTOP];
    ki[tid] = sel_idx[((size_t)a * NB + b) * KTOP + tid];
    kv[tid] = sel_val[((size_t)a * NB + b) * KTOP + tid];
    // bitonic sort ascending by index
    for (int k = 2; k <= KTOP; k <<= 1) {
        for (int j = k >> 1; j > 0; j >>= 1) {
            __syncthreads();
            int ixj = tid ^ j;
            if (ixj > tid) {
                uint32_t a0 = ki[tid], a1 = ki[ixj];
                float v0 = kv[tid], v1 = kv[ixj];
                bool up = ((tid & k) == 0);
                bool sw = up ? (a0 > a1) : (a0 < a1);
                if (sw) { ki[tid] = a1; ki[ixj] = a0; kv[tid] = v1; kv[ixj] = v0; }
            }
        }
    }
    __syncthreads();
    support_idx[b * KTOP + tid] = ki[tid];
    support_val[b * KTOP + tid] = kv[tid];
    if (tid == 0) support_cnt[b] = KTOP;
}

// ---------------- final output: zero + scatter ----------------
__global__ void k_outzero(float4* __restrict__ out) {
    int i = blockIdx.x * 256 + threadIdx.x;
    if (i < (NB * CHW) / 4) out[i] = make_float4(0.f, 0.f, 0.f, 0.f);
}

__global__ void k_scatter(const uint32_t* __restrict__ support_idx, const float* __restrict__ support_val,
                          float* __restrict__ out) {
    int b = blockIdx.x, tid = threadIdx.x;
    if (tid < KTOP) out[(size_t)b * CHW + support_idx[b * KTOP + tid]] = support_val[b * KTOP + tid];
}

// ---------------- host ----------------
static size_t align256(size_t x) { return (x + 255) & ~(size_t)255; }

extern "C" void kernel_launch(void* const* d_in, const int* in_sizes, int n_in,
                              void* d_out, int out_size, void* d_ws, size_t ws_size,
                              hipStream_t stream)
{
    const float* Y = (const float*)d_in[0];   // (32,1,64,64)
    const float* W = (const float*)d_in[1];   // (128,1,8,8), normalized
    float* out = (float*)d_out;               // (32,128,57,57) — doubles as dense g

    char* p = (char*)d_ws;
    size_t off = 0;
    auto carve = [&](size_t bytes) { void* r = p + off; off = align256(off + bytes); return r; };
    float*    Rg          = (float*)   carve(NB * IMG2 * sizeof(float));
    uint32_t* hist        = (uint32_t*)carve(NB * NBUCK * sizeof(uint32_t));
    uint32_t* thr         = (uint32_t*)carve(NB * sizeof(uint32_t));
    int*      cand_cnt    = (int*)     carve(NB * NS * sizeof(int));
    double*   l2part      = (double*)  carve(NB * sizeof(double));
    double*   err         = (double*)  carve(NATT * NB * sizeof(double));
    int*      sel_a       = (int*)     carve(sizeof(int));
    int*      support_cnt = (int*)     carve(NB * sizeof(int));
    uint32_t* support_idx = (uint32_t*)carve(NB * KTOP * sizeof(uint32_t));
    float*    support_val = (float*)   carve(NB * KTOP * sizeof(float));
    uint32_t* sel_idx     = (uint32_t*)carve((size_t)NATT * NB * KTOP * sizeof(uint32_t));
    float*    sel_val     = (float*)   carve((size_t)NATT * NB * KTOP * sizeof(float));
    uint32_t* cand_idx    = (uint32_t*)carve((size_t)NB * NS * SCAP * sizeof(uint32_t));
    float*    cand_g      = (float*)   carve((size_t)NB * NS * SCAP * sizeof(float));
    uint32_t* c2_idx      = (uint32_t*)carve((size_t)NB * CAP2 * sizeof(uint32_t));
    float*    c2_g        = (float*)   carve((size_t)NB * CAP2 * sizeof(float));
    float*    c2_x        = (float*)   carve((size_t)NB * CAP2 * sizeof(float));
    int*      nc_out      = (int*)     carve(NB * sizeof(int));
    (void)ws_size; (void)in_sizes; (void)n_in; (void)out_size;  // ~9.4 MB total

    k_init<<<1, 64, 0, stream>>>(support_cnt);
    for (int t = 0; t < 3; ++t) {
        k_zero<<<(NB * NBUCK + 255) / 256, 256, 0, stream>>>(hist, cand_cnt);
        k_resid<<<NB, 256, 0, stream>>>(Y, W, support_cnt, support_idx, support_val, Rg, l2part);
        k_conv<<<dim3(NB, NCH / 2), 256, 0, stream>>>(Rg, W, out, hist);
        k_thresh<<<1, 64, 0, stream>>>(hist, thr);
        k_collect<<<dim3((CHW / 4 + 255) / 256, NB), 256, 0, stream>>>(out, thr, cand_cnt, cand_idx, cand_g);
        k_suppg<<<NB, 256, 0, stream>>>(out, thr, support_cnt, support_idx, support_val,
                                        cand_cnt, cand_idx, cand_g, c2_idx, c2_g, c2_x, nc_out);
        k_attempt<<<dim3(NATT, NB), 256, 0, stream>>>(Y, W, nc_out, c2_idx, c2_g, c2_x,
                                                      sel_idx, sel_val, err);
        k_select<<<1, 64, 0, stream>>>(l2part, err, sel_a);
        k_update<<<NB, 256, 0, stream>>>(sel_a, sel_idx, sel_val, support_cnt, support_idx, support_val);
    }
    k_outzero<<<((NB * CHW) / 4 + 255) / 256, 256, 0, stream>>>((float4*)out);
    k_scatter<<<NB, 256, 0, stream>>>(support_idx, support_val, out);
}

// Round 3
// 998.267 us; speedup vs baseline: 2.6263x; 1.4983x over previous
//
#include <hip/hip_runtime.h>
#include <stdint.h>

// ---- problem constants ----
#define NB   32        // batch
#define NCH  128       // num atoms
#define IMG  64
#define IMG2 4096      // 64*64
#define OH   57        // 64-8+1
#define OHW  3249      // 57*57
#define CHW  415872    // 128*3249 (per-sample code size)
#define KTOP 256       // sparsity K
#define NATT 17        // alphas 2^0 .. 2^-16 (while count<=15 semantics)
#define NS   32        // candidate counter slices per sample (atomic spread)
#define SCAP 512       // capacity per slice
#define CAP2 8192      // compacted candidate capacity per sample
#define NBUCK 2048     // |g| histogram buckets (top 11 bits of float)
#define TGT  900       // collect at least this many top-|g| entries (need >=512)

// ---------------- init: support count = 0 ----------------
__global__ void k_init(int* support_cnt) {
    if (threadIdx.x < NB) support_cnt[threadIdx.x] = 0;
}

// ---------------- zero hist + sliced cand counters ----------------
__global__ void k_zero(uint32_t* hist, int* cand_cnt) {
    int i = blockIdx.x * 256 + threadIdx.x;
    if (i < NB * NBUCK) hist[i] = 0;
    if (i < NB * NS) cand_cnt[i] = 0;
}

// ---------------- R = Y - D*X (sparse scatter), l2 = sum R^2 ----------------
__global__ __launch_bounds__(256) void k_resid(
    const float* __restrict__ Y, const float* __restrict__ W,
    const int* __restrict__ support_cnt, const uint32_t* __restrict__ support_idx,
    const float* __restrict__ support_val, float* __restrict__ Rg, double* __restrict__ l2part)
{
    int b = blockIdx.x, tid = threadIdx.x;
    __shared__ float Rs[IMG2];
    const float4* Y4 = (const float4*)(Y + b * IMG2);
    float4* R4 = (float4*)Rs;
    for (int i = tid; i < IMG2 / 4; i += 256) R4[i] = Y4[i];
    __syncthreads();
    int n = support_cnt[b];
    for (int task = tid; task < n * 64; task += 256) {
        int i = task >> 6, tap = task & 63, p = tap >> 3, q = tap & 7;
        uint32_t idx = support_idx[b * KTOP + i];
        float val = support_val[b * KTOP + i];
        int c = idx / OHW, rem = idx % OHW, s = rem / OH, t = rem % OH;
        float w = W[c * 64 + p * 8 + q];              // W[c,0,p,q]
        atomicAdd(&Rs[(s + p) * IMG + (t + q)], -val * w);
    }
    __syncthreads();
    double acc = 0.0;
    for (int i = tid; i < IMG2; i += 256) {
        float v = Rs[i];
        Rg[b * IMG2 + i] = v;
        acc += (double)v * (double)v;
    }
    __shared__ double red[256];
    red[tid] = acc; __syncthreads();
    for (int s2 = 128; s2 > 0; s2 >>= 1) { if (tid < s2) red[tid] += red[tid + s2]; __syncthreads(); }
    if (tid == 0) l2part[b] = red[0];
}

// ---------------- g = D^T * R (dense, fp32 vector) + |g| histogram ----------------
// grid (NB, 64): 2 channels per block. Thread tile: 8 rows x 4 cols of g.
// g[b,c,s,t] = sum_{p,q} R[s+p,t+q] * W[c,0,q,p]   (Wt = swapaxes(W,2,3))
__global__ __launch_bounds__(256) void k_conv(
    const float* __restrict__ Rg, const float* __restrict__ W,
    float* __restrict__ g_out, uint32_t* __restrict__ hist)
{
    int b = blockIdx.x, cg = blockIdx.y, tid = threadIdx.x;
    __shared__ float Rs[72 * 72];
    __shared__ uint32_t hl[NBUCK];
    for (int i = tid; i < 72 * 72; i += 256) Rs[i] = 0.f;
    for (int i = tid; i < NBUCK; i += 256) hl[i] = 0u;
    __syncthreads();
    const float4* R4 = (const float4*)(Rg + b * IMG2);
    for (int i = tid; i < 1024; i += 256) {
        int row = i >> 4, col4 = (i & 15) * 4;
        *(float4*)&Rs[row * 72 + col4] = R4[i];
    }
    __syncthreads();
    int csub = tid >> 7;               // wave-uniform (waves 0,1 -> 0; 2,3 -> 1)
    int tile = tid & 127;              // valid < 120
    bool active = tile < 120;
    int tr = active ? tile / 15 : 0;
    int tc = active ? tile % 15 : 0;
    int s0 = tr * 8, t0 = tc * 4;
    int c = cg * 2 + csub;
    int c_s = __builtin_amdgcn_readfirstlane(c);   // force scalar weight loads
    const float* Wc = W + c_s * 64;

    float acc[8][4];
#pragma unroll
    for (int r = 0; r < 8; ++r)
#pragma unroll
        for (int cc = 0; cc < 4; ++cc) acc[r][cc] = 0.f;

#pragma unroll
    for (int rho = 0; rho < 15; ++rho) {
        float rb[12];
        const float* rp = &Rs[(s0 + rho) * 72 + t0];
        *(float4*)&rb[0] = *(const float4*)rp;
        *(float4*)&rb[4] = *(const float4*)(rp + 4);
        *(float4*)&rb[8] = *(const float4*)(rp + 8);
#pragma unroll
        for (int r = 0; r < 8; ++r) {
            const int p = rho - r;
            if (p >= 0 && p < 8) {
#pragma unroll
                for (int q = 0; q < 8; ++q) {
                    float wv = Wc[q * 8 + p];      // Wt[c,0,p,q] = W[c,0,q,p]
#pragma unroll
                    for (int cc = 0; cc < 4; ++cc)
                        acc[r][cc] = fmaf(rb[cc + q], wv, acc[r][cc]);
                }
            }
        }
    }
    if (active) {
        float* go = g_out + (size_t)(b * NCH + c) * OHW;
#pragma unroll
        for (int r = 0; r < 8; ++r) {
            int s = s0 + r;
            if (s < OH) {
#pragma unroll
                for (int cc = 0; cc < 4; ++cc) {
                    int t = t0 + cc;
                    if (t < OH) {
                        float v = acc[r][cc];
                        go[s * OH + t] = v;
                        uint32_t bits = __float_as_uint(v) & 0x7fffffffu;
                        atomicAdd(&hl[bits >> 21], 1u);
                    }
                }
            }
        }
    }
    __syncthreads();
    for (int i = tid; i < NBUCK; i += 256) {
        uint32_t v = hl[i];
        if (v) atomicAdd(&hist[b * NBUCK + i], v);
    }
}

// ---------------- per-sample bucket threshold: top >= TGT entries ----------------
// Parallel suffix-scan version: 256 threads x 8 buckets, Hillis-Steele in LDS.
// Reproduces the serial descending-scan break semantics exactly.
__global__ __launch_bounds__(256) void k_thresh(const uint32_t* __restrict__ hist,
                                                uint32_t* __restrict__ thr) {
    int b = blockIdx.x, tid = threadIdx.x;
    uint32_t h[8];
    uint32_t s = 0;
    const uint32_t* hb = hist + b * NBUCK + tid * 8;
#pragma unroll
    for (int k = 0; k < 8; ++k) { h[k] = hb[k]; s += h[k]; }
    __shared__ uint32_t buf[2][256];
    int cur = 0;
    buf[0][tid] = s;
    __syncthreads();
    for (int d = 1; d < 256; d <<= 1) {
        uint32_t v = buf[cur][tid];
        if (tid + d < 256) v += buf[cur][tid + d];
        buf[cur ^ 1][tid] = v;
        cur ^= 1;
        __syncthreads();
    }
    uint32_t sufme = buf[cur][tid];                       // sum over segments >= tid
    uint32_t base  = (tid < 255) ? buf[cur][tid + 1] : 0u; // sum over segments > tid
    if (tid == 0 && buf[cur][0] < TGT) thr[b] = 0u;       // total < TGT fallback (never hit)
    if (base < TGT && sufme >= TGT) {                     // unique crossing segment
        uint32_t acc = base; int bk = 0;
#pragma unroll
        for (int k = 7; k >= 0; --k) {
            acc += h[k];
            if (acc >= TGT) { bk = tid * 8 + k; break; }
        }
        thr[b] = (uint32_t)bk << 21;
    }
}

// ---------------- collect candidates: |g| above bucket threshold ----------------
// grid ((CHW/4+255)/256, NB); 4 elements per thread.
// Sliced counters (NS per sample) to avoid same-cacheline atomic serialization.
__global__ __launch_bounds__(256) void k_collect(
    const float* __restrict__ g, const uint32_t* __restrict__ thr,
    int* __restrict__ cand_cnt, uint32_t* __restrict__ cand_idx, float* __restrict__ cand_g)
{
    int b = blockIdx.y;
    int i4 = blockIdx.x * 256 + threadIdx.x;
    if (i4 >= CHW / 4) return;
    int slice = blockIdx.x & (NS - 1);
    uint32_t tb = thr[b];
    float4 v4 = ((const float4*)(g + (size_t)b * CHW))[i4];
    float vv[4] = { v4.x, v4.y, v4.z, v4.w };
#pragma unroll
    for (int k = 0; k < 4; ++k) {
        uint32_t bits = __float_as_uint(vv[k]) & 0x7fffffffu;
        if (bits >= tb) {
            int pos = atomicAdd(&cand_cnt[b * NS + slice], 1);
            if (pos < SCAP) {
                cand_idx[(b * NS + slice) * SCAP + pos] = (uint32_t)(i4 * 4 + k);
                cand_g[(b * NS + slice) * SCAP + pos] = vv[k];
            }
        }
    }
}

// ---------------- compact slices; add missing support entries; resolve x ----------------
__global__ __launch_bounds__(256) void k_suppg(
    const float* __restrict__ g, const uint32_t* __restrict__ thr,
    const int* __restrict__ support_cnt, const uint32_t* __restrict__ support_idx,
    const float* __restrict__ support_val,
    const int* __restrict__ cand_cnt, const uint32_t* __restrict__ cand_idx,
    const float* __restrict__ cand_g,
    uint32_t* __restrict__ c2_idx, float* __restrict__ c2_g, float* __restrict__ c2_x,
    int* __restrict__ nc_out)
{
    int b = blockIdx.x, tid = threadIdx.x;
    __shared__ uint32_t sidx[KTOP];
    __shared__ float sval[KTOP];
    __shared__ int cnts[NS];
    __shared__ int soff[NS + 1];
    __shared__ int nc_sh, extra;
    int n = support_cnt[b];
    if (tid < NS) cnts[tid] = min(cand_cnt[b * NS + tid], SCAP);
    if (tid < n) { sidx[tid] = support_idx[b * KTOP + tid]; sval[tid] = support_val[b * KTOP + tid]; }
    __syncthreads();
    if (tid == 0) {
        int acc = 0;
        for (int s = 0; s < NS; ++s) { soff[s] = acc; acc += cnts[s]; }
        soff[NS] = acc;
        nc_sh = min(acc, CAP2);
        extra = 0;
    }
    __syncthreads();
    // compact segmented -> contiguous
    for (int t = tid; t < NS * SCAP; t += 256) {
        int s = t >> 9, j = t & (SCAP - 1);
        if (j < cnts[s]) {
            int d = soff[s] + j;
            if (d < CAP2) {
                c2_idx[b * CAP2 + d] = cand_idx[(b * NS + s) * SCAP + j];
                c2_g[b * CAP2 + d] = cand_g[(b * NS + s) * SCAP + j];
            }
        }
    }
    __syncthreads();
    // append support entries below threshold (not collected)
    if (tid < n) {
        uint32_t idx = sidx[tid];
        float gv = g[(size_t)b * CHW + idx];
        uint32_t bits = __float_as_uint(gv) & 0x7fffffffu;
        if (bits < thr[b]) {
            int p = atomicAdd(&extra, 1);
            int d = nc_sh + p;
            if (d < CAP2) { c2_idx[b * CAP2 + d] = idx; c2_g[b * CAP2 + d] = gv; }
        }
    }
    __syncthreads();
    int nc = min(nc_sh + extra, CAP2);
    if (tid == 0) nc_out[b] = nc;
    // resolve x for all candidates (binary search over sorted support)
    for (int j = tid; j < nc; j += 256) {
        uint32_t q = c2_idx[b * CAP2 + j];
        float x = 0.f;
        int lo = 0, hi = n - 1;
        while (lo <= hi) {
            int mid = (lo + hi) >> 1;
            uint32_t m = sidx[mid];
            if (m == q) { x = sval[mid]; break; }
            if (m < q) lo = mid + 1; else hi = mid - 1;
        }
        c2_x[b * CAP2 + j] = x;
    }
}

// ---------------- one line-search attempt: exact top-256 + err ----------------
// grid (NATT, NB). v_i = x_i + alpha*g_i (fmaf form, identical across passes).
__global__ __launch_bounds__(256) void k_attempt(
    const float* __restrict__ Y, const float* __restrict__ W,
    const int* __restrict__ nc_in, const uint32_t* __restrict__ cand_idx,
    const float* __restrict__ cand_g, const float* __restrict__ cand_x,
    uint32_t* __restrict__ sel_idx, float* __restrict__ sel_val, double* __restrict__ err)
{
    int a = blockIdx.x, b = blockIdx.y, tid = threadIdx.x;
    float alpha = ldexpf(1.f, -a);
    int nc = min(nc_in[b], CAP2);
    const uint32_t* ci = cand_idx + b * CAP2;
    const float* cgp = cand_g + b * CAP2;
    const float* cxp = cand_x + b * CAP2;

    __shared__ uint32_t hl[256];
    __shared__ uint32_t sh_prefix;
    __shared__ int sh_rem;
    __shared__ int nsel, ntie;
    __shared__ uint32_t s_cidx[KTOP];
    __shared__ float s_v[KTOP];
    __shared__ uint32_t tie_i[512];
    __shared__ float recon[IMG2];
    __shared__ double red[256];

    if (tid == 0) { sh_prefix = 0u; sh_rem = KTOP; nsel = 0; ntie = 0; }
    s_cidx[tid] = 0u; s_v[tid] = 0.f;
    __syncthreads();

    // 4-pass radix select (descending) for the exact 256th-largest |v| bit pattern
    for (int pass = 0; pass < 4; ++pass) {
        hl[tid] = 0u;
        __syncthreads();
        uint32_t pre = sh_prefix;
        int shift = 24 - 8 * pass;
        for (int i = tid; i < nc; i += 256) {
            float v = fmaf(alpha, cgp[i], cxp[i]);
            uint32_t key = __float_as_uint(fabsf(v));
            bool ok = (pass == 0) || ((key >> (shift + 8)) == pre);
            if (ok) atomicAdd(&hl[(key >> shift) & 255], 1u);
        }
        __syncthreads();
        if (tid == 0) {
            uint32_t cum = 0; int rem = sh_rem; uint32_t pre2 = sh_prefix;
            for (int bin = 255; bin >= 0; --bin) {
                uint32_t cnt = hl[bin];
                if (cum + cnt >= (uint32_t)rem) {
                    sh_rem = rem - (int)cum;
                    sh_prefix = (pre2 << 8) | (uint32_t)bin;
                    break;
                }
                cum += cnt;
            }
        }
        __syncthreads();
    }
    uint32_t T = sh_prefix; int rem = sh_rem;

    // gather strictly-greater + ties
    for (int i = tid; i < nc; i += 256) {
        float v = fmaf(alpha, cgp[i], cxp[i]);
        uint32_t key = __float_as_uint(fabsf(v));
        if (key > T) {
            int p = atomicAdd(&nsel, 1);
            if (p < KTOP) { s_cidx[p] = ci[i]; s_v[p] = v; }
        } else if (key == T) {
            int p = atomicAdd(&ntie, 1);
            if (p < 512) tie_i[p] = (uint32_t)i;
        }
    }
    __syncthreads();
    if (tid == 0) {
        int nt = min(ntie, 512);
        int base = min(nsel, KTOP);
        for (int k = 0; k < rem && base + k < KTOP; ++k) {   // smallest flat idx first (lax.top_k tie order)
            uint32_t best = 0xffffffffu; int bj = -1;
            for (int j = 0; j < nt; ++j) {
                uint32_t t2 = tie_i[j];
                if (t2 == 0xffffffffu) continue;
                uint32_t fidx = ci[t2];
                if (fidx < best) { best = fidx; bj = j; }
            }
            if (bj < 0) break;
            uint32_t i2 = tie_i[bj]; tie_i[bj] = 0xffffffffu;
            float v = fmaf(alpha, cgp[i2], cxp[i2]);
            s_cidx[base + k] = ci[i2]; s_v[base + k] = v;
        }
    }
    __syncthreads();
    sel_idx[((size_t)a * NB + b) * KTOP + tid] = s_cidx[tid];
    sel_val[((size_t)a * NB + b) * KTOP + tid] = s_v[tid];

    // reconstruction + err
    for (int i = tid; i < IMG2; i += 256) recon[i] = 0.f;
    __syncthreads();
    for (int task = tid; task < KTOP * 64; task += 256) {
        int i = task >> 6, tap = task & 63, p = tap >> 3, q = tap & 7;
        uint32_t idx = s_cidx[i];
        float val = s_v[i];
        int c = idx / OHW, remn = idx % OHW, s = remn / OH, t = remn % OH;
        atomicAdd(&recon[(s + p) * IMG + (t + q)], val * W[c * 64 + p * 8 + q]);
    }
    __syncthreads();
    double accd = 0.0;
    for (int e = tid; e < IMG2; e += 256) {
        float d = Y[b * IMG2 + e] - recon[e];
        accd += (double)d * (double)d;
    }
    red[tid] = accd; __syncthreads();
    for (int s2 = 128; s2 > 0; s2 >>= 1) { if (tid < s2) red[tid] += red[tid + s2]; __syncthreads(); }
    if (tid == 0) err[a * NB + b] = red[0];
}

// ---------------- replay while-loop: first alpha with err < l2_start ----------------
__global__ void k_select(const double* __restrict__ l2part, const double* __restrict__ err,
                         int* __restrict__ sel_a) {
    if (threadIdx.x != 0 || blockIdx.x != 0) return;
    double l2 = 0.0;
    for (int b = 0; b < NB; ++b) l2 += l2part[b];
    int sel = NATT - 1;
    for (int a = 0; a < NATT; ++a) {
        double e = 0.0;
        for (int b = 0; b < NB; ++b) e += err[a * NB + b];
        if (e < l2) { sel = a; break; }
    }
    *sel_a = sel;
}

// ---------------- adopt selected attempt as new X (sorted support) ----------------
__global__ __launch_bounds__(256) void k_update(
    const int* __restrict__ sel_a, const uint32_t* __restrict__ sel_idx, const float* __restrict__ sel_val,
    int* __restrict__ support_cnt, uint32_t* __restrict__ support_idx, float* __restrict__ support_val)
{
    int b = blockIdx.x, tid = threadIdx.x;
    int a = *sel_a;
    __shared__ uint32_t ki[KTOP];
    __shared__ float kv[KTOP];
    ki[tid] = sel_idx[((size_t)a * NB + b) * KTOP + tid];
    kv[tid] = sel_val[((size_t)a * NB + b) * KTOP + tid];
    // bitonic sort ascending by index
    for (int k = 2; k <= KTOP; k <<= 1) {
        for (int j = k >> 1; j > 0; j >>= 1) {
            __syncthreads();
            int ixj = tid ^ j;
            if (ixj > tid) {
                uint32_t a0 = ki[tid], a1 = ki[ixj];
                float v0 = kv[tid], v1 = kv[ixj];
                bool up = ((tid & k) == 0);
                bool sw = up ? (a0 > a1) : (a0 < a1);
                if (sw) { ki[tid] = a1; ki[ixj] = a0; kv[tid] = v1; kv[ixj] = v0; }
            }
        }
    }
    __syncthreads();
    support_idx[b * KTOP + tid] = ki[tid];
    support_val[b * KTOP + tid] = kv[tid];
    if (tid == 0) support_cnt[b] = KTOP;
}

// ---------------- final output: zero + scatter ----------------
__global__ void k_outzero(float4* __restrict__ out) {
    int i = blockIdx.x * 256 + threadIdx.x;
    if (i < (NB * CHW) / 4) out[i] = make_float4(0.f, 0.f, 0.f, 0.f);
}

__global__ void k_scatter(const uint32_t* __restrict__ support_idx, const float* __restrict__ support_val,
                          float* __restrict__ out) {
    int b = blockIdx.x, tid = threadIdx.x;
    if (tid < KTOP) out[(size_t)b * CHW + support_idx[b * KTOP + tid]] = support_val[b * KTOP + tid];
}

// ---------------- host ----------------
static size_t align256(size_t x) { return (x + 255) & ~(size_t)255; }

extern "C" void kernel_launch(void* const* d_in, const int* in_sizes, int n_in,
                              void* d_out, int out_size, void* d_ws, size_t ws_size,
                              hipStream_t stream)
{
    const float* Y = (const float*)d_in[0];   // (32,1,64,64)
    const float* W = (const float*)d_in[1];   // (128,1,8,8), normalized
    float* out = (float*)d_out;               // (32,128,57,57) — doubles as dense g

    char* p = (char*)d_ws;
    size_t off = 0;
    auto carve = [&](size_t bytes) { void* r = p + off; off = align256(off + bytes); return r; };
    float*    Rg          = (float*)   carve(NB * IMG2 * sizeof(float));
    uint32_t* hist        = (uint32_t*)carve(NB * NBUCK * sizeof(uint32_t));
    uint32_t* thr         = (uint32_t*)carve(NB * sizeof(uint32_t));
    int*      cand_cnt    = (int*)     carve(NB * NS * sizeof(int));
    double*   l2part      = (double*)  carve(NB * sizeof(double));
    double*   err         = (double*)  carve(NATT * NB * sizeof(double));
    int*      sel_a       = (int*)     carve(sizeof(int));
    int*      support_cnt = (int*)     carve(NB * sizeof(int));
    uint32_t* support_idx = (uint32_t*)carve(NB * KTOP * sizeof(uint32_t));
    float*    support_val = (float*)   carve(NB * KTOP * sizeof(float));
    uint32_t* sel_idx     = (uint32_t*)carve((size_t)NATT * NB * KTOP * sizeof(uint32_t));
    float*    sel_val     = (float*)   carve((size_t)NATT * NB * KTOP * sizeof(float));
    uint32_t* cand_idx    = (uint32_t*)carve((size_t)NB * NS * SCAP * sizeof(uint32_t));
    float*    cand_g      = (float*)   carve((size_t)NB * NS * SCAP * sizeof(float));
    uint32_t* c2_idx      = (uint32_t*)carve((size_t)NB * CAP2 * sizeof(uint32_t));
    float*    c2_g        = (float*)   carve((size_t)NB * CAP2 * sizeof(float));
    float*    c2_x        = (float*)   carve((size_t)NB * CAP2 * sizeof(float));
    int*      nc_out      = (int*)     carve(NB * sizeof(int));
    (void)ws_size; (void)in_sizes; (void)n_in; (void)out_size;  // ~9.4 MB total

    k_init<<<1, 64, 0, stream>>>(support_cnt);
    for (int t = 0; t < 3; ++t) {
        k_zero<<<(NB * NBUCK + 255) / 256, 256, 0, stream>>>(hist, cand_cnt);
        k_resid<<<NB, 256, 0, stream>>>(Y, W, support_cnt, support_idx, support_val, Rg, l2part);
        k_conv<<<dim3(NB, NCH / 2), 256, 0, stream>>>(Rg, W, out, hist);
        k_thresh<<<NB, 256, 0, stream>>>(hist, thr);
        k_collect<<<dim3((CHW / 4 + 255) / 256, NB), 256, 0, stream>>>(out, thr, cand_cnt, cand_idx, cand_g);
        k_suppg<<<NB, 256, 0, stream>>>(out, thr, support_cnt, support_idx, support_val,
                                        cand_cnt, cand_idx, cand_g, c2_idx, c2_g, c2_x, nc_out);
        k_attempt<<<dim3(NATT, NB), 256, 0, stream>>>(Y, W, nc_out, c2_idx, c2_g, c2_x,
                                                      sel_idx, sel_val, err);
        k_select<<<1, 64, 0, stream>>>(l2part, err, sel_a);
        k_update<<<NB, 256, 0, stream>>>(sel_a, sel_idx, sel_val, support_cnt, support_idx, support_val);
    }
    k_outzero<<<((NB * CHW) / 4 + 255) / 256, 256, 0, stream>>>((float4*)out);
    k_scatter<<<NB, 256, 0, stream>>>(support_idx, support_val, out);
}

// Round 4
// 878.220 us; speedup vs baseline: 2.9853x; 1.1367x over previous
//
#include <hip/hip_runtime.h>
#include <stdint.h>

// ---- problem constants ----
#define NB   32        // batch
#define NCH  128       // num atoms
#define IMG  64
#define IMG2 4096      // 64*64
#define OH   57        // 64-8+1
#define OHW  3249      // 57*57
#define CHW  415872    // 128*3249 (per-sample code size)
#define KTOP 256       // sparsity K
#define NATT 17        // alphas 2^0 .. 2^-16 (while count<=15 semantics)
#define NS   32        // candidate counter slices per sample (atomic spread)
#define SCAP 512       // capacity per slice
#define CAP2 8192      // compacted candidate capacity per sample
#define NBUCK 2048     // |g| histogram buckets (top 11 bits of float)
#define TGT  900       // collect at least this many top-|g| entries (need >=512)
#define RSTRIDE 72     // recon LDS row stride: (8p+q) covers 0..63 -> 2-way banks (free)

// ---------------- init: support count = 0 ----------------
__global__ void k_init(int* support_cnt) {
    if (threadIdx.x < NB) support_cnt[threadIdx.x] = 0;
}

// ---------------- zero hist + sliced cand counters ----------------
__global__ void k_zero(uint32_t* hist, int* cand_cnt) {
    int i = blockIdx.x * 256 + threadIdx.x;
    if (i < NB * NBUCK) hist[i] = 0;
    if (i < NB * NS) cand_cnt[i] = 0;
}

// ---------------- R = Y - D*X (sparse scatter), l2 = sum R^2 ----------------
__global__ __launch_bounds__(256) void k_resid(
    const float* __restrict__ Y, const float* __restrict__ W,
    const int* __restrict__ support_cnt, const uint32_t* __restrict__ support_idx,
    const float* __restrict__ support_val, float* __restrict__ Rg, double* __restrict__ l2part)
{
    int b = blockIdx.x, tid = threadIdx.x;
    __shared__ float Rs[IMG2];
    const float4* Y4 = (const float4*)(Y + b * IMG2);
    float4* R4 = (float4*)Rs;
    for (int i = tid; i < IMG2 / 4; i += 256) R4[i] = Y4[i];
    __syncthreads();
    int n = support_cnt[b];
    for (int task = tid; task < n * 64; task += 256) {
        int i = task >> 6, tap = task & 63, p = tap >> 3, q = tap & 7;
        uint32_t idx = support_idx[b * KTOP + i];
        float val = support_val[b * KTOP + i];
        int c = idx / OHW, rem = idx % OHW, s = rem / OH, t = rem % OH;
        float w = W[c * 64 + p * 8 + q];              // W[c,0,p,q]
        atomicAdd(&Rs[(s + p) * IMG + (t + q)], -val * w);
    }
    __syncthreads();
    double acc = 0.0;
    for (int i = tid; i < IMG2; i += 256) {
        float v = Rs[i];
        Rg[b * IMG2 + i] = v;
        acc += (double)v * (double)v;
    }
    __shared__ double red[256];
    red[tid] = acc; __syncthreads();
    for (int s2 = 128; s2 > 0; s2 >>= 1) { if (tid < s2) red[tid] += red[tid + s2]; __syncthreads(); }
    if (tid == 0) l2part[b] = red[0];
}

// ---------------- g = D^T * R (dense, fp32 vector) + |g| histogram ----------------
__global__ __launch_bounds__(256) void k_conv(
    const float* __restrict__ Rg, const float* __restrict__ W,
    float* __restrict__ g_out, uint32_t* __restrict__ hist)
{
    int b = blockIdx.x, cg = blockIdx.y, tid = threadIdx.x;
    __shared__ float Rs[72 * 72];
    __shared__ uint32_t hl[NBUCK];
    for (int i = tid; i < 72 * 72; i += 256) Rs[i] = 0.f;
    for (int i = tid; i < NBUCK; i += 256) hl[i] = 0u;
    __syncthreads();
    const float4* R4 = (const float4*)(Rg + b * IMG2);
    for (int i = tid; i < 1024; i += 256) {
        int row = i >> 4, col4 = (i & 15) * 4;
        *(float4*)&Rs[row * 72 + col4] = R4[i];
    }
    __syncthreads();
    int csub = tid >> 7;               // wave-uniform
    int tile = tid & 127;              // valid < 120
    bool active = tile < 120;
    int tr = active ? tile / 15 : 0;
    int tc = active ? tile % 15 : 0;
    int s0 = tr * 8, t0 = tc * 4;
    int c = cg * 2 + csub;
    int c_s = __builtin_amdgcn_readfirstlane(c);
    const float* Wc = W + c_s * 64;

    float acc[8][4];
#pragma unroll
    for (int r = 0; r < 8; ++r)
#pragma unroll
        for (int cc = 0; cc < 4; ++cc) acc[r][cc] = 0.f;

#pragma unroll
    for (int rho = 0; rho < 15; ++rho) {
        float rb[12];
        const float* rp = &Rs[(s0 + rho) * 72 + t0];
        *(float4*)&rb[0] = *(const float4*)rp;
        *(float4*)&rb[4] = *(const float4*)(rp + 4);
        *(float4*)&rb[8] = *(const float4*)(rp + 8);
#pragma unroll
        for (int r = 0; r < 8; ++r) {
            const int p = rho - r;
            if (p >= 0 && p < 8) {
#pragma unroll
                for (int q = 0; q < 8; ++q) {
                    float wv = Wc[q * 8 + p];      // Wt[c,0,p,q] = W[c,0,q,p]
#pragma unroll
                    for (int cc = 0; cc < 4; ++cc)
                        acc[r][cc] = fmaf(rb[cc + q], wv, acc[r][cc]);
                }
            }
        }
    }
    if (active) {
        float* go = g_out + (size_t)(b * NCH + c) * OHW;
#pragma unroll
        for (int r = 0; r < 8; ++r) {
            int s = s0 + r;
            if (s < OH) {
#pragma unroll
                for (int cc = 0; cc < 4; ++cc) {
                    int t = t0 + cc;
                    if (t < OH) {
                        float v = acc[r][cc];
                        go[s * OH + t] = v;
                        uint32_t bits = __float_as_uint(v) & 0x7fffffffu;
                        atomicAdd(&hl[bits >> 21], 1u);
                    }
                }
            }
        }
    }
    __syncthreads();
    for (int i = tid; i < NBUCK; i += 256) {
        uint32_t v = hl[i];
        if (v) atomicAdd(&hist[b * NBUCK + i], v);
    }
}

// ---------------- per-sample bucket threshold (parallel suffix scan) ----------------
__global__ __launch_bounds__(256) void k_thresh(const uint32_t* __restrict__ hist,
                                                uint32_t* __restrict__ thr) {
    int b = blockIdx.x, tid = threadIdx.x;
    uint32_t h[8];
    uint32_t s = 0;
    const uint32_t* hb = hist + b * NBUCK + tid * 8;
#pragma unroll
    for (int k = 0; k < 8; ++k) { h[k] = hb[k]; s += h[k]; }
    __shared__ uint32_t buf[2][256];
    int cur = 0;
    buf[0][tid] = s;
    __syncthreads();
    for (int d = 1; d < 256; d <<= 1) {
        uint32_t v = buf[cur][tid];
        if (tid + d < 256) v += buf[cur][tid + d];
        buf[cur ^ 1][tid] = v;
        cur ^= 1;
        __syncthreads();
    }
    uint32_t sufme = buf[cur][tid];
    uint32_t base  = (tid < 255) ? buf[cur][tid + 1] : 0u;
    if (tid == 0 && buf[cur][0] < TGT) thr[b] = 0u;
    if (base < TGT && sufme >= TGT) {
        uint32_t acc = base; int bk = 0;
#pragma unroll
        for (int k = 7; k >= 0; --k) {
            acc += h[k];
            if (acc >= TGT) { bk = tid * 8 + k; break; }
        }
        thr[b] = (uint32_t)bk << 21;
    }
}

// ---------------- collect candidates: |g| above bucket threshold ----------------
__global__ __launch_bounds__(256) void k_collect(
    const float* __restrict__ g, const uint32_t* __restrict__ thr,
    int* __restrict__ cand_cnt, uint32_t* __restrict__ cand_idx, float* __restrict__ cand_g)
{
    int b = blockIdx.y;
    int i4 = blockIdx.x * 256 + threadIdx.x;
    if (i4 >= CHW / 4) return;
    int slice = blockIdx.x & (NS - 1);
    uint32_t tb = thr[b];
    float4 v4 = ((const float4*)(g + (size_t)b * CHW))[i4];
    float vv[4] = { v4.x, v4.y, v4.z, v4.w };
#pragma unroll
    for (int k = 0; k < 4; ++k) {
        uint32_t bits = __float_as_uint(vv[k]) & 0x7fffffffu;
        if (bits >= tb) {
            int pos = atomicAdd(&cand_cnt[b * NS + slice], 1);
            if (pos < SCAP) {
                cand_idx[(b * NS + slice) * SCAP + pos] = (uint32_t)(i4 * 4 + k);
                cand_g[(b * NS + slice) * SCAP + pos] = vv[k];
            }
        }
    }
}

// ---------------- compact slices; add missing support entries; resolve x ----------------
__global__ __launch_bounds__(256) void k_suppg(
    const float* __restrict__ g, const uint32_t* __restrict__ thr,
    const int* __restrict__ support_cnt, const uint32_t* __restrict__ support_idx,
    const float* __restrict__ support_val,
    const int* __restrict__ cand_cnt, const uint32_t* __restrict__ cand_idx,
    const float* __restrict__ cand_g,
    uint32_t* __restrict__ c2_idx, float* __restrict__ c2_g, float* __restrict__ c2_x,
    int* __restrict__ nc_out)
{
    int b = blockIdx.x, tid = threadIdx.x;
    __shared__ uint32_t sidx[KTOP];
    __shared__ float sval[KTOP];
    __shared__ int cnts[NS];
    __shared__ int soff[NS + 1];
    __shared__ int nc_sh, extra;
    int n = support_cnt[b];
    if (tid < NS) cnts[tid] = min(cand_cnt[b * NS + tid], SCAP);
    if (tid < n) { sidx[tid] = support_idx[b * KTOP + tid]; sval[tid] = support_val[b * KTOP + tid]; }
    __syncthreads();
    if (tid == 0) {
        int acc = 0;
        for (int s = 0; s < NS; ++s) { soff[s] = acc; acc += cnts[s]; }
        soff[NS] = acc;
        nc_sh = min(acc, CAP2);
        extra = 0;
    }
    __syncthreads();
    for (int t = tid; t < NS * SCAP; t += 256) {
        int s = t >> 9, j = t & (SCAP - 1);
        if (j < cnts[s]) {
            int d = soff[s] + j;
            if (d < CAP2) {
                c2_idx[b * CAP2 + d] = cand_idx[(b * NS + s) * SCAP + j];
                c2_g[b * CAP2 + d] = cand_g[(b * NS + s) * SCAP + j];
            }
        }
    }
    __syncthreads();
    if (tid < n) {
        uint32_t idx = sidx[tid];
        float gv = g[(size_t)b * CHW + idx];
        uint32_t bits = __float_as_uint(gv) & 0x7fffffffu;
        if (bits < thr[b]) {
            int p = atomicAdd(&extra, 1);
            int d = nc_sh + p;
            if (d < CAP2) { c2_idx[b * CAP2 + d] = idx; c2_g[b * CAP2 + d] = gv; }
        }
    }
    __syncthreads();
    int nc = min(nc_sh + extra, CAP2);
    if (tid == 0) nc_out[b] = nc;
    for (int j = tid; j < nc; j += 256) {
        uint32_t q = c2_idx[b * CAP2 + j];
        float x = 0.f;
        int lo = 0, hi = n - 1;
        while (lo <= hi) {
            int mid = (lo + hi) >> 1;
            uint32_t m = sidx[mid];
            if (m == q) { x = sval[mid]; break; }
            if (m < q) lo = mid + 1; else hi = mid - 1;
        }
        c2_x[b * CAP2 + j] = x;
    }
}

// ---------------- one line-search attempt: exact top-256 + err ----------------
// grid (NATT, NB). Parallel suffix-scan radix select + parallel tie rank.
__global__ __launch_bounds__(256) void k_attempt(
    const float* __restrict__ Y, const float* __restrict__ W,
    const int* __restrict__ nc_in, const uint32_t* __restrict__ cand_idx,
    const float* __restrict__ cand_g, const float* __restrict__ cand_x,
    uint32_t* __restrict__ sel_idx, float* __restrict__ sel_val, double* __restrict__ err)
{
    int a = blockIdx.x, b = blockIdx.y, tid = threadIdx.x;
    float alpha = ldexpf(1.f, -a);
    int nc = min(nc_in[b], CAP2);
    const uint32_t* ci = cand_idx + b * CAP2;
    const float* cgp = cand_g + b * CAP2;
    const float* cxp = cand_x + b * CAP2;

    __shared__ uint32_t hl[256];
    __shared__ uint32_t sbuf[2][256];
    __shared__ uint32_t sh_prefix;
    __shared__ int sh_rem;
    __shared__ int nsel, ntie;
    __shared__ uint32_t s_cidx[KTOP];
    __shared__ float s_v[KTOP];
    __shared__ uint32_t tie_i[512];
    __shared__ uint32_t tie_f[512];
    __shared__ float recon[64 * RSTRIDE];
    __shared__ double red[256];

    if (tid == 0) { sh_prefix = 0u; sh_rem = KTOP; nsel = 0; ntie = 0; }
    s_cidx[tid] = 0u; s_v[tid] = 0.f;
    __syncthreads();

    // 4-pass radix select (descending) for the exact 256th-largest |v| bit pattern
    for (int pass = 0; pass < 4; ++pass) {
        uint32_t pre = sh_prefix;
        int rem = sh_rem;
        hl[tid] = 0u;
        __syncthreads();
        int shift = 24 - 8 * pass;
        for (int i = tid; i < nc; i += 256) {
            float v = fmaf(alpha, cgp[i], cxp[i]);
            uint32_t key = __float_as_uint(fabsf(v));
            bool ok = (pass == 0) || ((key >> (shift + 8)) == pre);
            if (ok) atomicAdd(&hl[(key >> shift) & 255], 1u);
        }
        __syncthreads();
        // parallel suffix scan over the 256 bins (replaces serial tid0 scan)
        sbuf[0][tid] = hl[tid];
        __syncthreads();
        int cur = 0;
        for (int d = 1; d < 256; d <<= 1) {
            uint32_t v = sbuf[cur][tid];
            if (tid + d < 256) v += sbuf[cur][tid + d];
            sbuf[cur ^ 1][tid] = v;
            cur ^= 1;
            __syncthreads();
        }
        uint32_t sufme = sbuf[cur][tid];
        uint32_t sufnx = (tid < 255) ? sbuf[cur][tid + 1] : 0u;
        if (sufme >= (uint32_t)rem && sufnx < (uint32_t)rem) {   // unique crossing bin
            sh_prefix = (pre << 8) | (uint32_t)tid;
            sh_rem = rem - (int)sufnx;
        }
        __syncthreads();
    }
    uint32_t T = sh_prefix; int rem = sh_rem;

    // gather strictly-greater + stage ties (flat index cached in LDS)
    for (int i = tid; i < nc; i += 256) {
        float v = fmaf(alpha, cgp[i], cxp[i]);
        uint32_t key = __float_as_uint(fabsf(v));
        if (key > T) {
            int p = atomicAdd(&nsel, 1);
            if (p < KTOP) { s_cidx[p] = ci[i]; s_v[p] = v; }
        } else if (key == T) {
            int p = atomicAdd(&ntie, 1);
            if (p < 512) { tie_i[p] = (uint32_t)i; tie_f[p] = ci[i]; }
        }
    }
    __syncthreads();
    // parallel tie-break: rank by flat index (smallest first = lax.top_k order)
    {
        int nt = min(ntie, 512);
        int base = min(nsel, KTOP - rem);   // invariant: nsel == KTOP - rem
        for (int j = tid; j < nt; j += 256) {
            uint32_t me = tie_f[j];
            int rank = 0;
            for (int j2 = 0; j2 < nt; ++j2) rank += (tie_f[j2] < me) ? 1 : 0;
            if (rank < rem && base + rank < KTOP) {
                uint32_t i2 = tie_i[j];
                s_cidx[base + rank] = me;
                s_v[base + rank] = fmaf(alpha, cgp[i2], cxp[i2]);
            }
        }
    }
    __syncthreads();
    sel_idx[((size_t)a * NB + b) * KTOP + tid] = s_cidx[tid];
    sel_val[((size_t)a * NB + b) * KTOP + tid] = s_v[tid];

    // reconstruction + err (stride-72 rows: 8p+q spans 0..63 -> 2-way banks, free)
    for (int i = tid; i < 64 * RSTRIDE; i += 256) recon[i] = 0.f;
    __syncthreads();
    for (int task = tid; task < KTOP * 64; task += 256) {
        int i = task >> 6, tap = task & 63, p = tap >> 3, q = tap & 7;
        uint32_t idx = s_cidx[i];
        float val = s_v[i];
        int c = idx / OHW, remn = idx % OHW, s = remn / OH, t = remn % OH;
        atomicAdd(&recon[(s + p) * RSTRIDE + (t + q)], val * W[c * 64 + p * 8 + q]);
    }
    __syncthreads();
    double accd = 0.0;
    for (int e = tid; e < IMG2; e += 256) {
        float d = Y[b * IMG2 + e] - recon[(e >> 6) * RSTRIDE + (e & 63)];
        accd += (double)d * (double)d;
    }
    red[tid] = accd; __syncthreads();
    for (int s2 = 128; s2 > 0; s2 >>= 1) { if (tid < s2) red[tid] += red[tid + s2]; __syncthreads(); }
    if (tid == 0) err[a * NB + b] = red[0];
}

// ---------------- replay while-loop: first alpha with err < l2_start ----------------
__global__ void k_select(const double* __restrict__ l2part, const double* __restrict__ err,
                         int* __restrict__ sel_a) {
    if (threadIdx.x != 0 || blockIdx.x != 0) return;
    double l2 = 0.0;
    for (int b = 0; b < NB; ++b) l2 += l2part[b];
    int sel = NATT - 1;
    for (int a = 0; a < NATT; ++a) {
        double e = 0.0;
        for (int b = 0; b < NB; ++b) e += err[a * NB + b];
        if (e < l2) { sel = a; break; }
    }
    *sel_a = sel;
}

// ---------------- adopt selected attempt as new X (sorted support) ----------------
__global__ __launch_bounds__(256) void k_update(
    const int* __restrict__ sel_a, const uint32_t* __restrict__ sel_idx, const float* __restrict__ sel_val,
    int* __restrict__ support_cnt, uint32_t* __restrict__ support_idx, float* __restrict__ support_val)
{
    int b = blockIdx.x, tid = threadIdx.x;
    int a = *sel_a;
    __shared__ uint32_t ki[KTOP];
    __shared__ float kv[KTOP];
    ki[tid] = sel_idx[((size_t)a * NB + b) * KTOP + tid];
    kv[tid] = sel_val[((size_t)a * NB + b) * KTOP + tid];
    for (int k = 2; k <= KTOP; k <<= 1) {
        for (int j = k >> 1; j > 0; j >>= 1) {
            __syncthreads();
            int ixj = tid ^ j;
            if (ixj > tid) {
                uint32_t a0 = ki[tid], a1 = ki[ixj];
                float v0 = kv[tid], v1 = kv[ixj];
                bool up = ((tid & k) == 0);
                bool sw = up ? (a0 > a1) : (a0 < a1);
                if (sw) { ki[tid] = a1; ki[ixj] = a0; kv[tid] = v1; kv[ixj] = v0; }
            }
        }
    }
    __syncthreads();
    support_idx[b * KTOP + tid] = ki[tid];
    support_val[b * KTOP + tid] = kv[tid];
    if (tid == 0) support_cnt[b] = KTOP;
}

// ---------------- final output: zero + scatter ----------------
__global__ void k_outzero(float4* __restrict__ out) {
    int i = blockIdx.x * 256 + threadIdx.x;
    if (i < (NB * CHW) / 4) out[i] = make_float4(0.f, 0.f, 0.f, 0.f);
}

__global__ void k_scatter(const uint32_t* __restrict__ support_idx, const float* __restrict__ support_val,
                          float* __restrict__ out) {
    int b = blockIdx.x, tid = threadIdx.x;
    if (tid < KTOP) out[(size_t)b * CHW + support_idx[b * KTOP + tid]] = support_val[b * KTOP + tid];
}

// ---------------- host ----------------
static size_t align256(size_t x) { return (x + 255) & ~(size_t)255; }

extern "C" void kernel_launch(void* const* d_in, const int* in_sizes, int n_in,
                              void* d_out, int out_size, void* d_ws, size_t ws_size,
                              hipStream_t stream)
{
    const float* Y = (const float*)d_in[0];   // (32,1,64,64)
    const float* W = (const float*)d_in[1];   // (128,1,8,8), normalized
    float* out = (float*)d_out;               // (32,128,57,57) — doubles as dense g

    char* p = (char*)d_ws;
    size_t off = 0;
    auto carve = [&](size_t bytes) { void* r = p + off; off = align256(off + bytes); return r; };
    float*    Rg          = (float*)   carve(NB * IMG2 * sizeof(float));
    uint32_t* hist        = (uint32_t*)carve(NB * NBUCK * sizeof(uint32_t));
    uint32_t* thr         = (uint32_t*)carve(NB * sizeof(uint32_t));
    int*      cand_cnt    = (int*)     carve(NB * NS * sizeof(int));
    double*   l2part      = (double*)  carve(NB * sizeof(double));
    double*   err         = (double*)  carve(NATT * NB * sizeof(double));
    int*      sel_a       = (int*)     carve(sizeof(int));
    int*      support_cnt = (int*)     carve(NB * sizeof(int));
    uint32_t* support_idx = (uint32_t*)carve(NB * KTOP * sizeof(uint32_t));
    float*    support_val = (float*)   carve(NB * KTOP * sizeof(float));
    uint32_t* sel_idx     = (uint32_t*)carve((size_t)NATT * NB * KTOP * sizeof(uint32_t));
    float*    sel_val     = (float*)   carve((size_t)NATT * NB * KTOP * sizeof(float));
    uint32_t* cand_idx    = (uint32_t*)carve((size_t)NB * NS * SCAP * sizeof(uint32_t));
    float*    cand_g      = (float*)   carve((size_t)NB * NS * SCAP * sizeof(float));
    uint32_t* c2_idx      = (uint32_t*)carve((size_t)NB * CAP2 * sizeof(uint32_t));
    float*    c2_g        = (float*)   carve((size_t)NB * CAP2 * sizeof(float));
    float*    c2_x        = (float*)   carve((size_t)NB * CAP2 * sizeof(float));
    int*      nc_out      = (int*)     carve(NB * sizeof(int));
    (void)ws_size; (void)in_sizes; (void)n_in; (void)out_size;

    k_init<<<1, 64, 0, stream>>>(support_cnt);
    for (int t = 0; t < 3; ++t) {
        k_zero<<<(NB * NBUCK + 255) / 256, 256, 0, stream>>>(hist, cand_cnt);
        k_resid<<<NB, 256, 0, stream>>>(Y, W, support_cnt, support_idx, support_val, Rg, l2part);
        k_conv<<<dim3(NB, NCH / 2), 256, 0, stream>>>(Rg, W, out, hist);
        k_thresh<<<NB, 256, 0, stream>>>(hist, thr);
        k_collect<<<dim3((CHW / 4 + 255) / 256, NB), 256, 0, stream>>>(out, thr, cand_cnt, cand_idx, cand_g);
        k_suppg<<<NB, 256, 0, stream>>>(out, thr, support_cnt, support_idx, support_val,
                                        cand_cnt, cand_idx, cand_g, c2_idx, c2_g, c2_x, nc_out);
        k_attempt<<<dim3(NATT, NB), 256, 0, stream>>>(Y, W, nc_out, c2_idx, c2_g, c2_x,
                                                      sel_idx, sel_val, err);
        k_select<<<1, 64, 0, stream>>>(l2part, err, sel_a);
        k_update<<<NB, 256, 0, stream>>>(sel_a, sel_idx, sel_val, support_cnt, support_idx, support_val);
    }
    k_outzero<<<((NB * CHW) / 4 + 255) / 256, 256, 0, stream>>>((float4*)out);
    k_scatter<<<NB, 256, 0, stream>>>(support_idx, support_val, out);
}

// Round 5
// 694.637 us; speedup vs baseline: 3.7743x; 1.2643x over previous
//
#include <hip/hip_runtime.h>
#include <stdint.h>

// ---- problem constants ----
#define NB   32        // batch
#define NCH  128       // num atoms
#define IMG  64
#define IMG2 4096      // 64*64
#define OH   57        // 64-8+1
#define OHW  3249      // 57*57
#define CHW  415872    // 128*3249 (per-sample code size)
#define KTOP 256       // sparsity K
#define NATT 17        // alphas 2^0 .. 2^-16 (while count<=15 semantics)
#define NS   32        // candidate counter slices per sample (atomic spread)
#define SCAP 512       // capacity per slice
#define CAP2 8192      // candidate buffer stride per sample
#define NCAP 2048      // candidate cap consumed by k_attempt (NREG*256)
#define NREG 8         // candidates cached in registers per thread
#define NBUCK 8192     // |g| histogram buckets (top 13 bits: sign+exp8+mant4)
#define HSHIFT 18      // bits >> 18 -> bucket
#define TGT  512       // collect at least top-512 of |g| (>= top-256 non-support + ties)
#define RSTRIDE 72     // recon LDS row stride: (8p+q) covers 0..63 -> 2-way banks (free)

// ---------------- init: support count = 0 ----------------
__global__ void k_init(int* support_cnt) {
    if (threadIdx.x < NB) support_cnt[threadIdx.x] = 0;
}

// ---------------- zero hist + sliced cand counters ----------------
__global__ void k_zero(uint32_t* hist, int* cand_cnt) {
    int i = blockIdx.x * 256 + threadIdx.x;
    if (i < NB * NBUCK) hist[i] = 0;
    if (i < NB * NS) cand_cnt[i] = 0;
}

// ---------------- R = Y - D*X (sparse scatter), l2 = sum R^2 ----------------
__global__ __launch_bounds__(256) void k_resid(
    const float* __restrict__ Y, const float* __restrict__ W,
    const int* __restrict__ support_cnt, const uint32_t* __restrict__ support_idx,
    const float* __restrict__ support_val, float* __restrict__ Rg, double* __restrict__ l2part)
{
    int b = blockIdx.x, tid = threadIdx.x;
    __shared__ float Rs[IMG2];
    const float4* Y4 = (const float4*)(Y + b * IMG2);
    float4* R4 = (float4*)Rs;
    for (int i = tid; i < IMG2 / 4; i += 256) R4[i] = Y4[i];
    __syncthreads();
    int n = support_cnt[b];
    for (int task = tid; task < n * 64; task += 256) {
        int i = task >> 6, tap = task & 63, p = tap >> 3, q = tap & 7;
        uint32_t idx = support_idx[b * KTOP + i];
        float val = support_val[b * KTOP + i];
        int c = idx / OHW, rem = idx % OHW, s = rem / OH, t = rem % OH;
        float w = W[c * 64 + p * 8 + q];              // W[c,0,p,q]
        atomicAdd(&Rs[(s + p) * IMG + (t + q)], -val * w);
    }
    __syncthreads();
    double acc = 0.0;
    for (int i = tid; i < IMG2; i += 256) {
        float v = Rs[i];
        Rg[b * IMG2 + i] = v;
        acc += (double)v * (double)v;
    }
    __shared__ double red[256];
    red[tid] = acc; __syncthreads();
    for (int s2 = 128; s2 > 0; s2 >>= 1) { if (tid < s2) red[tid] += red[tid + s2]; __syncthreads(); }
    if (tid == 0) l2part[b] = red[0];
}

// ---------------- g = D^T * R (dense, fp32 vector) + fine |g| histogram ----------------
// grid (NB, 16): 8 channels per block (4 pairs, inner loop) to amortize the 32KB hist.
__global__ __launch_bounds__(256) void k_conv(
    const float* __restrict__ Rg, const float* __restrict__ W,
    float* __restrict__ g_out, uint32_t* __restrict__ hist)
{
    int b = blockIdx.x, cg0 = blockIdx.y, tid = threadIdx.x;
    __shared__ float Rs[71 * 72];
    __shared__ uint32_t hl[NBUCK];
    for (int i = tid; i < 71 * 72; i += 256) Rs[i] = 0.f;
    for (int i = tid; i < NBUCK; i += 256) hl[i] = 0u;
    __syncthreads();
    const float4* R4 = (const float4*)(Rg + b * IMG2);
    for (int i = tid; i < 1024; i += 256) {
        int row = i >> 4, col4 = (i & 15) * 4;
        *(float4*)&Rs[row * 72 + col4] = R4[i];
    }
    __syncthreads();
    int csub = tid >> 7;               // wave-uniform
    int tile = tid & 127;              // valid < 120
    bool active = tile < 120;
    int tr = active ? tile / 15 : 0;
    int tc = active ? tile % 15 : 0;
    int s0 = tr * 8, t0 = tc * 4;

    for (int sub = 0; sub < 4; ++sub) {
        int c = cg0 * 8 + sub * 2 + csub;
        int c_s = __builtin_amdgcn_readfirstlane(c);
        const float* Wc = W + c_s * 64;

        float acc[8][4];
#pragma unroll
        for (int r = 0; r < 8; ++r)
#pragma unroll
            for (int cc = 0; cc < 4; ++cc) acc[r][cc] = 0.f;

#pragma unroll
        for (int rho = 0; rho < 15; ++rho) {
            float rb[12];
            const float* rp = &Rs[(s0 + rho) * 72 + t0];
            *(float4*)&rb[0] = *(const float4*)rp;
            *(float4*)&rb[4] = *(const float4*)(rp + 4);
            *(float4*)&rb[8] = *(const float4*)(rp + 8);
#pragma unroll
            for (int r = 0; r < 8; ++r) {
                const int p = rho - r;
                if (p >= 0 && p < 8) {
#pragma unroll
                    for (int q = 0; q < 8; ++q) {
                        float wv = Wc[q * 8 + p];      // Wt[c,0,p,q] = W[c,0,q,p]
#pragma unroll
                        for (int cc = 0; cc < 4; ++cc)
                            acc[r][cc] = fmaf(rb[cc + q], wv, acc[r][cc]);
                    }
                }
            }
        }
        if (active) {
            float* go = g_out + (size_t)(b * NCH + c) * OHW;
#pragma unroll
            for (int r = 0; r < 8; ++r) {
                int s = s0 + r;
                if (s < OH) {
#pragma unroll
                    for (int cc = 0; cc < 4; ++cc) {
                        int t = t0 + cc;
                        if (t < OH) {
                            float v = acc[r][cc];
                            go[s * OH + t] = v;
                            uint32_t bits = __float_as_uint(v) & 0x7fffffffu;
                            atomicAdd(&hl[bits >> HSHIFT], 1u);
                        }
                    }
                }
            }
        }
    }
    __syncthreads();
    for (int i = tid; i < NBUCK; i += 256) {
        uint32_t v = hl[i];
        if (v) atomicAdd(&hist[b * NBUCK + i], v);
    }
}

// ---------------- per-sample bucket threshold (parallel suffix scan) ----------------
__global__ __launch_bounds__(256) void k_thresh(const uint32_t* __restrict__ hist,
                                                uint32_t* __restrict__ thr) {
    int b = blockIdx.x, tid = threadIdx.x;
    uint32_t h[32];
    uint32_t s = 0;
    const uint32_t* hb = hist + b * NBUCK + tid * 32;
#pragma unroll
    for (int k = 0; k < 32; ++k) { h[k] = hb[k]; s += h[k]; }
    __shared__ uint32_t buf[2][256];
    int cur = 0;
    buf[0][tid] = s;
    __syncthreads();
    for (int d = 1; d < 256; d <<= 1) {
        uint32_t v = buf[cur][tid];
        if (tid + d < 256) v += buf[cur][tid + d];
        buf[cur ^ 1][tid] = v;
        cur ^= 1;
        __syncthreads();
    }
    uint32_t sufme = buf[cur][tid];
    uint32_t base  = (tid < 255) ? buf[cur][tid + 1] : 0u;
    if (tid == 0 && buf[cur][0] < TGT) thr[b] = 0u;       // fallback (never hit)
    if (base < TGT && sufme >= TGT) {                     // unique crossing segment
        uint32_t acc = base; int bk = 0;
#pragma unroll
        for (int k = 31; k >= 0; --k) {
            acc += h[k];
            if (acc >= TGT) { bk = tid * 32 + k; break; }
        }
        thr[b] = (uint32_t)bk << HSHIFT;
    }
}

// ---------------- collect candidates: |g| above bucket threshold ----------------
__global__ __launch_bounds__(256) void k_collect(
    const float* __restrict__ g, const uint32_t* __restrict__ thr,
    int* __restrict__ cand_cnt, uint32_t* __restrict__ cand_idx, float* __restrict__ cand_g)
{
    int b = blockIdx.y;
    int i4 = blockIdx.x * 256 + threadIdx.x;
    if (i4 >= CHW / 4) return;
    int slice = blockIdx.x & (NS - 1);
    uint32_t tb = thr[b];
    float4 v4 = ((const float4*)(g + (size_t)b * CHW))[i4];
    float vv[4] = { v4.x, v4.y, v4.z, v4.w };
#pragma unroll
    for (int k = 0; k < 4; ++k) {
        uint32_t bits = __float_as_uint(vv[k]) & 0x7fffffffu;
        if (bits >= tb) {
            int pos = atomicAdd(&cand_cnt[b * NS + slice], 1);
            if (pos < SCAP) {
                cand_idx[(b * NS + slice) * SCAP + pos] = (uint32_t)(i4 * 4 + k);
                cand_g[(b * NS + slice) * SCAP + pos] = vv[k];
            }
        }
    }
}

// ---------------- support-first append; compact slices; resolve x ----------------
__global__ __launch_bounds__(256) void k_suppg(
    const float* __restrict__ g, const uint32_t* __restrict__ thr,
    const int* __restrict__ support_cnt, const uint32_t* __restrict__ support_idx,
    const float* __restrict__ support_val,
    const int* __restrict__ cand_cnt, const uint32_t* __restrict__ cand_idx,
    const float* __restrict__ cand_g,
    uint32_t* __restrict__ c2_idx, float* __restrict__ c2_g, float* __restrict__ c2_x,
    int* __restrict__ nc_out)
{
    int b = blockIdx.x, tid = threadIdx.x;
    __shared__ uint32_t sidx[KTOP];
    __shared__ float sval[KTOP];
    __shared__ int cnts[NS];
    __shared__ int soff[NS + 1];
    __shared__ int extra;
    int n = support_cnt[b];
    if (tid < NS) cnts[tid] = min(cand_cnt[b * NS + tid], SCAP);
    if (tid == 0) extra = 0;
    if (tid < n) { sidx[tid] = support_idx[b * KTOP + tid]; sval[tid] = support_val[b * KTOP + tid]; }
    __syncthreads();
    // support entries below threshold go FIRST (guaranteed present)
    if (tid < n) {
        uint32_t idx = sidx[tid];
        float gv = g[(size_t)b * CHW + idx];
        uint32_t bits = __float_as_uint(gv) & 0x7fffffffu;
        if (bits < thr[b]) {
            int p = atomicAdd(&extra, 1);
            c2_idx[b * CAP2 + p] = idx; c2_g[b * CAP2 + p] = gv;
        }
    }
    __syncthreads();
    __shared__ int nc_sh;
    if (tid == 0) {
        int acc = extra;
        for (int s = 0; s < NS; ++s) { soff[s] = acc; acc += cnts[s]; }
        soff[NS] = acc;
        nc_sh = min(acc, NCAP);
        nc_out[b] = nc_sh;
    }
    __syncthreads();
    for (int t = tid; t < NS * SCAP; t += 256) {
        int s = t >> 9, j = t & (SCAP - 1);
        if (j < cnts[s]) {
            int d = soff[s] + j;
            if (d < NCAP) {
                c2_idx[b * CAP2 + d] = cand_idx[(b * NS + s) * SCAP + j];
                c2_g[b * CAP2 + d] = cand_g[(b * NS + s) * SCAP + j];
            }
        }
    }
    __syncthreads();
    int nc = nc_sh;
    for (int j = tid; j < nc; j += 256) {
        uint32_t q = c2_idx[b * CAP2 + j];
        float x = 0.f;
        int lo = 0, hi = n - 1;
        while (lo <= hi) {
            int mid = (lo + hi) >> 1;
            uint32_t m = sidx[mid];
            if (m == q) { x = sval[mid]; break; }
            if (m < q) lo = mid + 1; else hi = mid - 1;
        }
        c2_x[b * CAP2 + j] = x;
    }
}

// ---------------- one line-search attempt: exact top-256 + err ----------------
// grid (NATT, NB). Candidates cached in registers; ballot-based binary select.
__global__ __launch_bounds__(256) void k_attempt(
    const float* __restrict__ Y, const float* __restrict__ W,
    const int* __restrict__ nc_in, const uint32_t* __restrict__ cand_idx,
    const float* __restrict__ cand_g, const float* __restrict__ cand_x,
    uint32_t* __restrict__ sel_idx, float* __restrict__ sel_val, double* __restrict__ err)
{
    int a = blockIdx.x, b = blockIdx.y, tid = threadIdx.x;
    int lane = tid & 63, wid = tid >> 6;
    float alpha = ldexpf(1.f, -a);
    int nc = min(nc_in[b], NCAP);
    const uint32_t* ci = cand_idx + b * CAP2;
    const float* cgp = cand_g + b * CAP2;
    const float* cxp = cand_x + b * CAP2;

    __shared__ int wcnt[2][4];
    __shared__ int nsel_sh, ntie_sh;
    __shared__ uint32_t s_cidx[KTOP];
    __shared__ float s_v[KTOP];
    __shared__ uint32_t tie_f[256];
    __shared__ float tie_v[256];
    __shared__ float recon[64 * RSTRIDE];
    __shared__ double red[256];

    // load phase: one coalesced pass, everything into registers
    float v[NREG]; uint32_t fi[NREG]; uint32_t kr[NREG];
#pragma unroll
    for (int j = 0; j < NREG; ++j) {
        int i = tid + 256 * j;
        bool ok = i < nc;
        float gg = ok ? cgp[i] : 0.f;
        float xx = ok ? cxp[i] : 0.f;
        fi[j] = ok ? ci[i] : 0xffffffffu;
        float vv = fmaf(alpha, gg, xx);
        v[j] = ok ? vv : 0.f;
        kr[j] = ok ? (__float_as_uint(vv) & 0x7fffffffu) : 0u;
    }
    if (tid == 0) { nsel_sh = 0; ntie_sh = 0; }
    s_cidx[tid] = 0u; s_v[tid] = 0.f;

    // 31-step binary search for T = exact 256th-largest |v| bit pattern
    uint32_t T = 0;
    for (int bit = 30; bit >= 0; --bit) {
        uint32_t tt = T | (1u << bit);
        int lc = 0;
#pragma unroll
        for (int j = 0; j < NREG; ++j) lc += (kr[j] >= tt) ? 1 : 0;
        for (int d = 32; d > 0; d >>= 1) lc += __shfl_xor(lc, d, 64);
        if (lane == 0) wcnt[bit & 1][wid] = lc;
        __syncthreads();
        int tot = wcnt[bit & 1][0] + wcnt[bit & 1][1] + wcnt[bit & 1][2] + wcnt[bit & 1][3];
        if (tot >= KTOP) T = tt;
    }

    // gather >T (wave-aggregated slots) + stage ==T ties
#pragma unroll
    for (int j = 0; j < NREG; ++j) {
        bool isg = (fi[j] != 0xffffffffu) && (kr[j] > T);
        unsigned long long m = __ballot(isg);
        if (m) {
            int base = 0;
            if (lane == 0) base = atomicAdd(&nsel_sh, __popcll(m));
            base = __shfl(base, 0, 64);
            if (isg) {
                int p = base + __popcll(m & ((1ull << lane) - 1ull));
                if (p < KTOP) { s_cidx[p] = fi[j]; s_v[p] = v[j]; }
            }
        }
        bool ist = (fi[j] != 0xffffffffu) && (kr[j] == T);
        unsigned long long m2 = __ballot(ist);
        if (m2) {
            int base2 = 0;
            if (lane == 0) base2 = atomicAdd(&ntie_sh, __popcll(m2));
            base2 = __shfl(base2, 0, 64);
            if (ist) {
                int p = base2 + __popcll(m2 & ((1ull << lane) - 1ull));
                if (p < 256) { tie_f[p] = fi[j]; tie_v[p] = v[j]; }
            }
        }
    }
    __syncthreads();
    int nsel = min(nsel_sh, KTOP);
    int rem = KTOP - nsel;
    int nt = min(ntie_sh, 256);
    // ties ranked by flat index ascending (= lax.top_k tie order), take first rem
    for (int j = tid; j < nt; j += 256) {
        uint32_t me = tie_f[j];
        int rank = 0;
        for (int j2 = 0; j2 < nt; ++j2) rank += (tie_f[j2] < me) ? 1 : 0;
        if (rank < rem) { s_cidx[nsel + rank] = me; s_v[nsel + rank] = tie_v[j]; }
    }
    __syncthreads();
    sel_idx[((size_t)a * NB + b) * KTOP + tid] = s_cidx[tid];
    sel_val[((size_t)a * NB + b) * KTOP + tid] = s_v[tid];

    // reconstruction + err (stride-72 rows: 8p+q spans 0..63 -> 2-way banks, free)
    for (int i = tid; i < 64 * RSTRIDE; i += 256) recon[i] = 0.f;
    __syncthreads();
    for (int task = tid; task < KTOP * 64; task += 256) {
        int i = task >> 6, tap = task & 63, p = tap >> 3, q = tap & 7;
        uint32_t idx = s_cidx[i];
        float val = s_v[i];
        int c = idx / OHW, remn = idx % OHW, s = remn / OH, t = remn % OH;
        atomicAdd(&recon[(s + p) * RSTRIDE + (t + q)], val * W[c * 64 + p * 8 + q]);
    }
    __syncthreads();
    double accd = 0.0;
    for (int e = tid; e < IMG2; e += 256) {
        float d = Y[b * IMG2 + e] - recon[(e >> 6) * RSTRIDE + (e & 63)];
        accd += (double)d * (double)d;
    }
    red[tid] = accd; __syncthreads();
    for (int s2 = 128; s2 > 0; s2 >>= 1) { if (tid < s2) red[tid] += red[tid + s2]; __syncthreads(); }
    if (tid == 0) err[a * NB + b] = red[0];
}

// ---------------- replay while-loop: first alpha with err < l2_start ----------------
__global__ void k_select(const double* __restrict__ l2part, const double* __restrict__ err,
                         int* __restrict__ sel_a) {
    int tid = threadIdx.x;
    __shared__ double esum[NATT + 1];
    if (tid < NATT) {
        double e = 0.0;
        for (int b2 = 0; b2 < NB; ++b2) e += err[tid * NB + b2];
        esum[tid] = e;
    } else if (tid == NATT) {
        double l2 = 0.0;
        for (int b2 = 0; b2 < NB; ++b2) l2 += l2part[b2];
        esum[NATT] = l2;
    }
    __syncthreads();
    if (tid == 0) {
        double l2 = esum[NATT];
        int sel = NATT - 1;
        for (int a2 = 0; a2 < NATT; ++a2) if (esum[a2] < l2) { sel = a2; break; }
        *sel_a = sel;
    }
}

// ---------------- adopt selected attempt as new X (sorted support) ----------------
__global__ __launch_bounds__(256) void k_update(
    const int* __restrict__ sel_a, const uint32_t* __restrict__ sel_idx, const float* __restrict__ sel_val,
    int* __restrict__ support_cnt, uint32_t* __restrict__ support_idx, float* __restrict__ support_val)
{
    int b = blockIdx.x, tid = threadIdx.x;
    int a = *sel_a;
    __shared__ uint32_t ki[KTOP];
    __shared__ float kv[KTOP];
    ki[tid] = sel_idx[((size_t)a * NB + b) * KTOP + tid];
    kv[tid] = sel_val[((size_t)a * NB + b) * KTOP + tid];
    for (int k = 2; k <= KTOP; k <<= 1) {
        for (int j = k >> 1; j > 0; j >>= 1) {
            __syncthreads();
            int ixj = tid ^ j;
            if (ixj > tid) {
                uint32_t a0 = ki[tid], a1 = ki[ixj];
                float v0 = kv[tid], v1 = kv[ixj];
                bool up = ((tid & k) == 0);
                bool sw = up ? (a0 > a1) : (a0 < a1);
                if (sw) { ki[tid] = a1; ki[ixj] = a0; kv[tid] = v1; kv[ixj] = v0; }
            }
        }
    }
    __syncthreads();
    support_idx[b * KTOP + tid] = ki[tid];
    support_val[b * KTOP + tid] = kv[tid];
    if (tid == 0) support_cnt[b] = KTOP;
}

// ---------------- final output: zero + scatter ----------------
__global__ void k_outzero(float4* __restrict__ out) {
    int i = blockIdx.x * 256 + threadIdx.x;
    if (i < (NB * CHW) / 4) out[i] = make_float4(0.f, 0.f, 0.f, 0.f);
}

__global__ void k_scatter(const uint32_t* __restrict__ support_idx, const float* __restrict__ support_val,
                          float* __restrict__ out) {
    int b = blockIdx.x, tid = threadIdx.x;
    if (tid < KTOP) out[(size_t)b * CHW + support_idx[b * KTOP + tid]] = support_val[b * KTOP + tid];
}

// ---------------- host ----------------
static size_t align256(size_t x) { return (x + 255) & ~(size_t)255; }

extern "C" void kernel_launch(void* const* d_in, const int* in_sizes, int n_in,
                              void* d_out, int out_size, void* d_ws, size_t ws_size,
                              hipStream_t stream)
{
    const float* Y = (const float*)d_in[0];   // (32,1,64,64)
    const float* W = (const float*)d_in[1];   // (128,1,8,8), normalized
    float* out = (float*)d_out;               // (32,128,57,57) — doubles as dense g

    char* p = (char*)d_ws;
    size_t off = 0;
    auto carve = [&](size_t bytes) { void* r = p + off; off = align256(off + bytes); return r; };
    float*    Rg          = (float*)   carve(NB * IMG2 * sizeof(float));
    uint32_t* hist        = (uint32_t*)carve((size_t)NB * NBUCK * sizeof(uint32_t));
    uint32_t* thr         = (uint32_t*)carve(NB * sizeof(uint32_t));
    int*      cand_cnt    = (int*)     carve(NB * NS * sizeof(int));
    double*   l2part      = (double*)  carve(NB * sizeof(double));
    double*   err         = (double*)  carve(NATT * NB * sizeof(double));
    int*      sel_a       = (int*)     carve(sizeof(int));
    int*      support_cnt = (int*)     carve(NB * sizeof(int));
    uint32_t* support_idx = (uint32_t*)carve(NB * KTOP * sizeof(uint32_t));
    float*    support_val = (float*)   carve(NB * KTOP * sizeof(float));
    uint32_t* sel_idx     = (uint32_t*)carve((size_t)NATT * NB * KTOP * sizeof(uint32_t));
    float*    sel_val     = (float*)   carve((size_t)NATT * NB * KTOP * sizeof(float));
    uint32_t* cand_idx    = (uint32_t*)carve((size_t)NB * NS * SCAP * sizeof(uint32_t));
    float*    cand_g      = (float*)   carve((size_t)NB * NS * SCAP * sizeof(float));
    uint32_t* c2_idx      = (uint32_t*)carve((size_t)NB * CAP2 * sizeof(uint32_t));
    float*    c2_g        = (float*)   carve((size_t)NB * CAP2 * sizeof(float));
    float*    c2_x        = (float*)   carve((size_t)NB * CAP2 * sizeof(float));
    int*      nc_out      = (int*)     carve(NB * sizeof(int));
    (void)ws_size; (void)in_sizes; (void)n_in; (void)out_size;  // ~10.3 MB total

    k_init<<<1, 64, 0, stream>>>(support_cnt);
    for (int t = 0; t < 3; ++t) {
        k_zero<<<(NB * NBUCK + 255) / 256, 256, 0, stream>>>(hist, cand_cnt);
        k_resid<<<NB, 256, 0, stream>>>(Y, W, support_cnt, support_idx, support_val, Rg, l2part);
        k_conv<<<dim3(NB, 16), 256, 0, stream>>>(Rg, W, out, hist);
        k_thresh<<<NB, 256, 0, stream>>>(hist, thr);
        k_collect<<<dim3((CHW / 4 + 255) / 256, NB), 256, 0, stream>>>(out, thr, cand_cnt, cand_idx, cand_g);
        k_suppg<<<NB, 256, 0, stream>>>(out, thr, support_cnt, support_idx, support_val,
                                        cand_cnt, cand_idx, cand_g, c2_idx, c2_g, c2_x, nc_out);
        k_attempt<<<dim3(NATT, NB), 256, 0, stream>>>(Y, W, nc_out, c2_idx, c2_g, c2_x,
                                                      sel_idx, sel_val, err);
        k_select<<<1, 64, 0, stream>>>(l2part, err, sel_a);
        k_update<<<NB, 256, 0, stream>>>(sel_a, sel_idx, sel_val, support_cnt, support_idx, support_val);
    }
    k_outzero<<<((NB * CHW) / 4 + 255) / 256, 256, 0, stream>>>((float4*)out);
    k_scatter<<<NB, 256, 0, stream>>>(support_idx, support_val, out);
}